// Round 13
// baseline (857.081 us; speedup 1.0000x reference)
//
#include <hip/hip_runtime.h>
#include <hip/hip_bf16.h>
#include <hip/hip_cooperative_groups.h>
#include <stdint.h>

namespace cg = cooperative_groups;

#define NN 4096
#define EMB 300
#define KP  320           // padded K for all GEMMs
#define NKT 10            // KP / 32
#define NPAD 384          // padded N for MLP weight tiles (3 x 128)

typedef __attribute__((ext_vector_type(8))) short short8;
typedef __attribute__((ext_vector_type(4))) float f32x4;

__device__ __forceinline__ float bf2f(unsigned short b) {
    return __uint_as_float(((unsigned int)b) << 16);
}
__device__ __forceinline__ float bflo(unsigned int u) {
    return __uint_as_float(u << 16);
}
__device__ __forceinline__ float bfhi(unsigned int u) {
    return __uint_as_float(u & 0xFFFF0000u);
}
__device__ __forceinline__ void split_store(float f, unsigned short* hi, unsigned short* lo) {
    __hip_bfloat16 hb = __float2bfloat16(f);
    float hf = __bfloat162float(hb);
    __hip_bfloat16 lb = __float2bfloat16(f - hf);
    *hi = *reinterpret_cast<unsigned short*>(&hb);
    *lo = *reinterpret_cast<unsigned short*>(&lb);
}
__device__ __forceinline__ unsigned short f2bfu(float f) {
    __hip_bfloat16 hb = __float2bfloat16(f);
    return *reinterpret_cast<unsigned short*>(&hb);
}

// Fragment-major layout for a [rows x 320] MFMA operand:
//   element (rowblk*16 + frow, kt*32 + kgrp*8 + e)  lives at
//   ((rowblk*NKT + kt)*64 + kgrp*16 + frow)*8 + e
__device__ __forceinline__ size_t fidx(int rowblk, int kt, int frow, int kgrp, int e) {
    return ((size_t)(rowblk * NKT + kt) * 64 + kgrp * 16 + frow) * 8 + e;
}

// ---------------------------------------------------------------------------
// prep_kernel (vectorized): blocks 0..1023 split_h (8 rows x 40 chunks),
// 1024..1119 W transpose-split, 1120..1145 rowssq zero, 1146 bias pad.
// ---------------------------------------------------------------------------
__global__ __launch_bounds__(320) void prep_kernel(
    const float* __restrict__ h0, const float* __restrict__ h1,
    const float* __restrict__ W1, const float* __restrict__ W2,
    const float* __restrict__ b1, const float* __restrict__ b2,
    unsigned short* __restrict__ Hhi, unsigned short* __restrict__ Hlo,
    unsigned short* __restrict__ W1th, unsigned short* __restrict__ W1tl,
    unsigned short* __restrict__ W2th, unsigned short* __restrict__ W2tl,
    float* __restrict__ b1p, float* __restrict__ b2p, float* __restrict__ rowssq)
{
    const int blk = blockIdx.x;
    const int tid = threadIdx.x;
    if (blk < 1024) {
        const int r = tid / 40, c = tid % 40;     // 8 rows x 40 k-chunks
        const int row = blk * 8 + r;
        const float* hp = (row < NN) ? h0 + (size_t)row * EMB
                                     : h1 + (size_t)(row - NN) * EMB;
        float v[8];
        #pragma unroll
        for (int e = 0; e < 8; ++e) {
            int k = c * 8 + e;
            v[e] = (k < EMB) ? hp[k] : 0.f;
        }
        short8 hiv, lov;
        #pragma unroll
        for (int e = 0; e < 8; ++e) {
            unsigned short h_, l_;
            split_store(v[e], &h_, &l_);
            hiv[e] = (short)h_; lov[e] = (short)l_;
        }
        size_t o = fidx(row >> 4, c >> 2, row & 15, c & 3, 0);
        *(short8*)(Hhi + o) = hiv;
        *(short8*)(Hlo + o) = lov;
    } else if (blk < 1120) {
        const int wb = blk - 1024;                // 96 blocks x 8 n
        const int nn = tid / 40, c = tid % 40;
        const int n = wb * 8 + nn;                // 0..767
        const int which = (n >= NPAD);
        const int nl = which ? n - NPAD : n;      // 0..383
        const float* W = which ? W2 : W1;
        unsigned short* Wh = which ? W2th : W1th;
        unsigned short* Wl = which ? W2tl : W1tl;
        short8 hiv, lov;
        #pragma unroll
        for (int e = 0; e < 8; ++e) {
            int k = c * 8 + e;
            float val = (nl < EMB && k < EMB) ? W[(size_t)k * EMB + nl] : 0.f;
            unsigned short h_, l_;
            split_store(val, &h_, &l_);
            hiv[e] = (short)h_; lov[e] = (short)l_;
        }
        size_t o = fidx(nl >> 4, c >> 2, nl & 15, c & 3, 0);
        *(short8*)(Wh + o) = hiv;
        *(short8*)(Wl + o) = lov;
    } else if (blk < 1146) {
        int i = (blk - 1120) * 320 + tid;
        if (i < 2 * NN) rowssq[i] = 0.f;
    } else {
        for (int x = tid; x < NPAD; x += 320) {
            b1p[x] = (x < EMB) ? b1[x] : 0.f;
            b2p[x] = (x < EMB) ? b2[x] : 0.f;
        }
    }
}

// ---------------------------------------------------------------------------
// Barrier-free fragment GEMM core: 128x128 tile, 4 waves (2x2), split-bf16.
// ---------------------------------------------------------------------------
#define BM 128
#define BN 128

#define GEMM_FRAG_CORE(Ahi_, Alo_, Bhi_, Blo_, ARB0, BRB0)                     \
    const int tid  = threadIdx.x;                                              \
    const int wave = tid >> 6;                                                 \
    const int lane = tid & 63;                                                 \
    const int wm   = wave >> 1, wn = wave & 1;                                 \
    const int frow = lane & 15;                                                \
    const int kgrp = lane >> 4;                                                \
    (void)tid;                                                                 \
    f32x4 acc[4][4];                                                           \
    _Pragma("unroll")                                                          \
    for (int m = 0; m < 4; ++m)                                                \
        _Pragma("unroll")                                                      \
        for (int n = 0; n < 4; ++n) acc[m][n] = (f32x4)0.f;                    \
    const int arb = (ARB0) + wm * 4;                                           \
    const int brb = (BRB0) + wn * 4;                                           \
    const size_t lo8 = (size_t)lane * 8;                                       \
    _Pragma("unroll 2")                                                        \
    for (int kt = 0; kt < NKT; ++kt) {                                         \
        short8 ahi[4], alo[4], bhi[4], blo[4];                                 \
        _Pragma("unroll")                                                      \
        for (int m = 0; m < 4; ++m) {                                          \
            size_t b = (size_t)((arb + m) * NKT + kt) * 512 + lo8;             \
            ahi[m] = *(const short8*)(Ahi_ + b);                               \
            alo[m] = *(const short8*)(Alo_ + b);                               \
        }                                                                      \
        _Pragma("unroll")                                                      \
        for (int n = 0; n < 4; ++n) {                                          \
            size_t b = (size_t)((brb + n) * NKT + kt) * 512 + lo8;             \
            bhi[n] = *(const short8*)(Bhi_ + b);                               \
            blo[n] = *(const short8*)(Blo_ + b);                               \
        }                                                                      \
        _Pragma("unroll")                                                      \
        for (int m = 0; m < 4; ++m)                                            \
            _Pragma("unroll")                                                  \
            for (int n = 0; n < 4; ++n) {                                      \
                acc[m][n] = __builtin_amdgcn_mfma_f32_16x16x32_bf16(ahi[m], bhi[n], acc[m][n], 0, 0, 0); \
                acc[m][n] = __builtin_amdgcn_mfma_f32_16x16x32_bf16(ahi[m], blo[n], acc[m][n], 0, 0, 0); \
                acc[m][n] = __builtin_amdgcn_mfma_f32_16x16x32_bf16(alo[m], bhi[n], acc[m][n], 0, 0, 0); \
            }                                                                  \
    }

// ---------------------------------------------------------------------------
// gemm_l1: Y = split( relu( H @ W1 + b1 ) )  -> Y fragment-major
// ---------------------------------------------------------------------------
__global__ __launch_bounds__(256) void gemm_l1_kernel(
    const unsigned short* __restrict__ Ahi, const unsigned short* __restrict__ Alo,
    const unsigned short* __restrict__ Bhi, const unsigned short* __restrict__ Blo,
    const float* __restrict__ b1p,
    unsigned short* __restrict__ Yhi, unsigned short* __restrict__ Ylo)
{
    const int bx = blockIdx.x % 3;
    const int by = blockIdx.x / 3;
    const int brow = by * BM, bcol = bx * BN;
    GEMM_FRAG_CORE(Ahi, Alo, Bhi, Blo, by * 8, bx * 8)

    #pragma unroll
    for (int n = 0; n < 4; ++n) {
        const int col = bcol + wn * 64 + n * 16 + frow;
        const float bb = b1p[col];
        const bool ok = col < KP;
        #pragma unroll
        for (int m = 0; m < 4; ++m) {
            const int rbase = brow + wm * 64 + m * 16 + kgrp * 4;
            f32x4 a = acc[m][n];
            #pragma unroll
            for (int q = 0; q < 4; ++q) {
                if (ok) {
                    float y = fmaxf(a[q] + bb, 0.f);
                    int row = rbase + q;
                    size_t o = fidx(row >> 4, col >> 5, row & 15, (col >> 3) & 3, col & 7);
                    split_store(y, &Yhi[o], &Ylo[o]);
                }
            }
        }
    }
}

// ---------------------------------------------------------------------------
// gemm_l2: Z = Y @ W2 + b2 (fp32 row-major), rowssq[row] += sum_j Z^2
// ---------------------------------------------------------------------------
__global__ __launch_bounds__(256) void gemm_l2_kernel(
    const unsigned short* __restrict__ Ahi, const unsigned short* __restrict__ Alo,
    const unsigned short* __restrict__ Bhi, const unsigned short* __restrict__ Blo,
    const float* __restrict__ b2p,
    float* __restrict__ Z, float* __restrict__ rowssq)
{
    const int bx = blockIdx.x % 3;
    const int by = blockIdx.x / 3;
    const int brow = by * BM, bcol = bx * BN;
    GEMM_FRAG_CORE(Ahi, Alo, Bhi, Blo, by * 8, bx * 8)

    float sq[4][4];
    #pragma unroll
    for (int m = 0; m < 4; ++m)
        #pragma unroll
        for (int q = 0; q < 4; ++q) sq[m][q] = 0.f;

    #pragma unroll
    for (int n = 0; n < 4; ++n) {
        const int col = bcol + wn * 64 + n * 16 + frow;
        const float bb = b2p[col];
        const bool ok = col < KP;
        #pragma unroll
        for (int m = 0; m < 4; ++m) {
            const int rbase = brow + wm * 64 + m * 16 + kgrp * 4;
            f32x4 a = acc[m][n];
            #pragma unroll
            for (int q = 0; q < 4; ++q) {
                float z = a[q] + bb;
                if (ok) Z[(size_t)(rbase + q) * KP + col] = z;
                else    z = 0.f;
                sq[m][q] = fmaf(z, z, sq[m][q]);
            }
        }
    }
    #pragma unroll
    for (int m = 0; m < 4; ++m)
        #pragma unroll
        for (int q = 0; q < 4; ++q) {
            float v2 = sq[m][q];
            #pragma unroll
            for (int off = 1; off <= 8; off <<= 1) v2 += __shfl_xor(v2, off, 64);
            if ((lane & 15) == 0)
                atomicAdd(&rowssq[brow + wm * 64 + m * 16 + kgrp * 4 + q], v2);
        }
}

// ---------------------------------------------------------------------------
// normalize (vectorized): f = Z * rsqrt-row-norm -> Fhi/Flo fragment-major
// ---------------------------------------------------------------------------
__global__ __launch_bounds__(320) void normalize_kernel(
    const float* __restrict__ Z, const float* __restrict__ rowssq,
    unsigned short* __restrict__ Fhi, unsigned short* __restrict__ Flo)
{
    const int tid = threadIdx.x;
    const int r = tid / 40, c = tid % 40;
    const int row = blockIdx.x * 8 + r;
    const float sc = 1.0f / fmaxf(sqrtf(rowssq[row]), 1e-12f);
    const float* zp = Z + (size_t)row * KP + c * 8;
    short8 hiv, lov;
    #pragma unroll
    for (int e = 0; e < 8; ++e) {
        unsigned short h_, l_;
        split_store(zp[e] * sc, &h_, &l_);
        hiv[e] = (short)h_; lov[e] = (short)l_;
    }
    size_t o = fidx(row >> 4, c >> 2, row & 15, c & 3, 0);
    *(short8*)(Fhi + o) = hiv;
    *(short8*)(Flo + o) = lov;
}

// ---------------------------------------------------------------------------
// gemm_exp256: S0 = exp((f0 f1^T)/T)+eps, 256x256 tile, 8 waves (2x4).
// 2-D patch swizzle for per-XCD L2 residency.  (frozen from R10)
// ---------------------------------------------------------------------------
__global__ __launch_bounds__(512, 2) void gemm_exp256_kernel(
    const unsigned short* __restrict__ Fhi, const unsigned short* __restrict__ Flo,
    unsigned short* __restrict__ Sb, float* __restrict__ tpart)
{
    __shared__ unsigned short tile[128 * 256];
    __shared__ float colsum[256];

    const int p   = blockIdx.x & 7;
    const int idx = blockIdx.x >> 3;
    const int by  = (p >> 2) * 8 + (idx >> 2);
    const int bx  = (p & 3) * 4 + (idx & 3);
    const int brow = by * 256, bcol = bx * 256;

    const int tid  = threadIdx.x;
    const int wave = tid >> 6;
    const int lane = tid & 63;
    const int wm   = wave >> 2;
    const int wn   = wave & 3;
    const int frow = lane & 15;
    const int kgrp = lane >> 4;

    f32x4 acc[8][4];
    #pragma unroll
    for (int m = 0; m < 8; ++m)
        #pragma unroll
        for (int n = 0; n < 4; ++n) acc[m][n] = (f32x4)0.f;

    const int arb = by * 16 + wm * 8;
    const int brb = 256 + bx * 16 + wn * 4;
    const size_t lo8 = (size_t)lane * 8;

    for (int kt = 0; kt < NKT; ++kt) {
        short8 bhi[4], blo[4];
        #pragma unroll
        for (int n = 0; n < 4; ++n) {
            size_t b = (size_t)((brb + n) * NKT + kt) * 512 + lo8;
            bhi[n] = *(const short8*)(Fhi + b);
            blo[n] = *(const short8*)(Flo + b);
        }
        short8 ahi[8], alo[8];
        #pragma unroll
        for (int m = 0; m < 8; ++m) {
            size_t b = (size_t)((arb + m) * NKT + kt) * 512 + lo8;
            ahi[m] = *(const short8*)(Fhi + b);
            alo[m] = *(const short8*)(Flo + b);
        }
        #pragma unroll
        for (int m = 0; m < 8; ++m)
            #pragma unroll
            for (int n = 0; n < 4; ++n) {
                acc[m][n] = __builtin_amdgcn_mfma_f32_16x16x32_bf16(ahi[m], bhi[n], acc[m][n], 0, 0, 0);
                acc[m][n] = __builtin_amdgcn_mfma_f32_16x16x32_bf16(ahi[m], blo[n], acc[m][n], 0, 0, 0);
                acc[m][n] = __builtin_amdgcn_mfma_f32_16x16x32_bf16(alo[m], bhi[n], acc[m][n], 0, 0, 0);
            }
    }

    const float SCALE = 36.067376022224085f;
    if (tid < 256) colsum[tid] = 0.f;
    __syncthreads();

    for (int pass = 0; pass < 2; ++pass) {
        if (wm == pass) {
            #pragma unroll
            for (int n = 0; n < 4; ++n) {
                const int cl = wn * 64 + n * 16 + frow;
                float cp = 0.f;
                #pragma unroll
                for (int m = 0; m < 8; ++m) {
                    const int rl = m * 16 + kgrp * 4;
                    f32x4 a = acc[m][n];
                    #pragma unroll
                    for (int q = 0; q < 4; ++q) {
                        float sv = exp2f(a[q] * SCALE) + 1e-10f;
                        cp += sv;
                        tile[(rl + q) * 256 + cl] = f2bfu(sv);
                    }
                }
                atomicAdd(&colsum[cl], cp);
            }
        }
        __syncthreads();
        const int rbase = brow + pass * 128;
        for (int i = tid; i < 128 * 256 / 8; i += 512) {
            int row = i >> 5, ch = i & 31;
            *(short8*)(Sb + (size_t)(rbase + row) * NN + bcol + ch * 8) =
                *(const short8*)(tile + row * 256 + ch * 8);
        }
        __syncthreads();
    }
    if (tid < 256) tpart[(size_t)by * NN + bcol + tid] = colsum[tid];
}

// ---------------------------------------------------------------------------
// sinkhorn_coop: entire Sinkhorn chain (i=1..9) + output in ONE cooperative
// kernel.  256 blocks x 512 threads; block holds its 16-row stripe of Sb in
// registers across all iterations.  Column sums reduced in-kernel via
// grid-wide sync (device-scope fence per G16 cross-XCD rules).
// ---------------------------------------------------------------------------
__global__ __launch_bounds__(512) void sinkhorn_coop_kernel(
    const unsigned short* __restrict__ Sb, const float* __restrict__ tpart,
    float* __restrict__ part, float* __restrict__ vglob,
    float* __restrict__ Out)
{
    cg::grid_group grid = cg::this_grid();
    __shared__ float vs[NN];          // 16 KB: inverted colsums (v)
    __shared__ float red[16][8];
    __shared__ float us[16];
    __shared__ float redc[32][16];
    const int tid = threadIdx.x;
    const int bid = blockIdx.x;
    const int wave = tid >> 6, lane = tid & 63;
    const int row0 = bid * 16;
    const int cbase = bid * 16;       // this block's 16 owned columns

    // load stripe into registers (one read of Sb for the whole chain)
    uint4 rv[16];
    #pragma unroll
    for (int r = 0; r < 16; ++r)
        rv[r] = *(const uint4*)(Sb + (size_t)(row0 + r) * NN + tid * 8);

    // phase 0: vglob = 1/colsum(tpart, np=16) for owned cols
    if (tid < 256) {
        const int kg = tid >> 4, c16 = tid & 15;
        redc[kg][c16] = tpart[(size_t)kg * NN + cbase + c16];
    }
    __syncthreads();
    if (tid < 16) {
        float s = 0.f;
        #pragma unroll
        for (int kg = 0; kg < 16; ++kg) s += redc[kg][tid];
        vglob[cbase + tid] = 1.0f / s;
    }
    __threadfence();
    grid.sync();

    for (int it = 0; it < 4; ++it) {               // pairs (i=1,2)..(i=7,8)
        // load v into LDS
        for (int i = tid; i < NN / 4; i += 512)
            ((float4*)vs)[i] = ((const float4*)vglob)[i];
        __syncthreads();
        const float4* vs4 = (const float4*)vs;
        const float4 va = vs4[tid * 2], vb = vs4[tid * 2 + 1];

        // row pass: us[r] = 1/(s_r . v)
        #pragma unroll
        for (int r = 0; r < 16; ++r) {
            float p = 0.f;
            p = fmaf(bflo(rv[r].x), va.x, p);
            p = fmaf(bfhi(rv[r].x), va.y, p);
            p = fmaf(bflo(rv[r].y), va.z, p);
            p = fmaf(bfhi(rv[r].y), va.w, p);
            p = fmaf(bflo(rv[r].z), vb.x, p);
            p = fmaf(bfhi(rv[r].z), vb.y, p);
            p = fmaf(bflo(rv[r].w), vb.z, p);
            p = fmaf(bfhi(rv[r].w), vb.w, p);
            #pragma unroll
            for (int off = 32; off >= 1; off >>= 1) p += __shfl_down(p, off, 64);
            if (lane == 0) red[r][wave] = p;
        }
        __syncthreads();
        if (tid < 16) {
            float s = 0.f;
            #pragma unroll
            for (int w = 0; w < 8; ++w) s += red[tid][w];
            us[tid] = 1.0f / s;
        }
        __syncthreads();

        // col pass: partials from registers
        float a[8];
        #pragma unroll
        for (int e = 0; e < 8; ++e) a[e] = 0.f;
        #pragma unroll
        for (int r = 0; r < 16; ++r) {
            const float ur = us[r];
            a[0] = fmaf(bflo(rv[r].x), ur, a[0]);
            a[1] = fmaf(bfhi(rv[r].x), ur, a[1]);
            a[2] = fmaf(bflo(rv[r].y), ur, a[2]);
            a[3] = fmaf(bfhi(rv[r].y), ur, a[3]);
            a[4] = fmaf(bflo(rv[r].z), ur, a[4]);
            a[5] = fmaf(bfhi(rv[r].z), ur, a[5]);
            a[6] = fmaf(bflo(rv[r].w), ur, a[6]);
            a[7] = fmaf(bfhi(rv[r].w), ur, a[7]);
        }
        float* pp = part + (size_t)bid * NN + tid * 8;
        *(float4*)(pp)     = make_float4(a[0], a[1], a[2], a[3]);
        *(float4*)(pp + 4) = make_float4(a[4], a[5], a[6], a[7]);
        __threadfence();
        grid.sync();

        // reduce 256 partials for owned cols -> vglob (inverted)
        {
            const int kg = tid >> 4, c16 = tid & 15;   // kg 0..31
            float s = 0.f;
            #pragma unroll
            for (int j = 0; j < 8; ++j)
                s += part[(size_t)(kg * 8 + j) * NN + cbase + c16];
            redc[kg][c16] = s;
        }
        __syncthreads();
        if (tid < 16) {
            float s = 0.f;
            #pragma unroll
            for (int kg = 0; kg < 32; ++kg) s += redc[kg][tid];
            vglob[cbase + tid] = 1.0f / s;
        }
        __threadfence();
        grid.sync();
    }

    // final: load v, u_i = 1/(s_i . v), Out = u_i * s_ij * v_j (fp32)
    for (int i = tid; i < NN / 4; i += 512)
        ((float4*)vs)[i] = ((const float4*)vglob)[i];
    __syncthreads();
    const float4* vs4 = (const float4*)vs;
    const float4 va = vs4[tid * 2], vb = vs4[tid * 2 + 1];
    #pragma unroll
    for (int r = 0; r < 16; ++r) {
        float p = 0.f;
        p = fmaf(bflo(rv[r].x), va.x, p);
        p = fmaf(bfhi(rv[r].x), va.y, p);
        p = fmaf(bflo(rv[r].y), va.z, p);
        p = fmaf(bfhi(rv[r].y), va.w, p);
        p = fmaf(bflo(rv[r].z), vb.x, p);
        p = fmaf(bfhi(rv[r].z), vb.y, p);
        p = fmaf(bflo(rv[r].w), vb.z, p);
        p = fmaf(bfhi(rv[r].w), vb.w, p);
        #pragma unroll
        for (int off = 32; off >= 1; off >>= 1) p += __shfl_down(p, off, 64);
        if (lane == 0) red[r][wave] = p;
    }
    __syncthreads();
    if (tid < 16) {
        float s = 0.f;
        #pragma unroll
        for (int w = 0; w < 8; ++w) s += red[tid][w];
        us[tid] = 1.0f / s;
    }
    __syncthreads();
    #pragma unroll
    for (int r = 0; r < 16; ++r) {
        const float ui = us[r];
        float* outp = Out + (size_t)(row0 + r) * NN + tid * 8;
        float4 o0, o1;
        o0.x = bflo(rv[r].x) * ui * va.x;
        o0.y = bfhi(rv[r].x) * ui * va.y;
        o0.z = bflo(rv[r].y) * ui * va.z;
        o0.w = bfhi(rv[r].y) * ui * va.w;
        o1.x = bflo(rv[r].z) * ui * vb.x;
        o1.y = bfhi(rv[r].z) * ui * vb.y;
        o1.z = bflo(rv[r].w) * ui * vb.z;
        o1.w = bfhi(rv[r].w) * ui * vb.w;
        *(float4*)(outp)     = o0;
        *(float4*)(outp + 4) = o1;
    }
}

// ---------------------------------------------------------------------------
// fallback gemm_exp (fp32 S, atomic colsums) for small-ws path
// ---------------------------------------------------------------------------
__global__ __launch_bounds__(256) void gemm_exp_kernel(
    const unsigned short* __restrict__ Ahi, const unsigned short* __restrict__ Alo,
    const unsigned short* __restrict__ Bhi, const unsigned short* __restrict__ Blo,
    float* __restrict__ S, float* __restrict__ tcol)
{
    __shared__ float colsum[BN];
    const int bx = blockIdx.x & 31;
    const int by = blockIdx.x >> 5;
    const int brow = by * BM, bcol = bx * BN;
    GEMM_FRAG_CORE(Ahi, Alo, Bhi, Blo, by * 8, 256 + bx * 8)

    const float SCALE = 36.067376022224085f;
    if (tid < BN) colsum[tid] = 0.f;
    __syncthreads();
    #pragma unroll
    for (int n = 0; n < 4; ++n) {
        const int col = bcol + wn * 64 + n * 16 + frow;
        float cp = 0.f;
        #pragma unroll
        for (int m = 0; m < 4; ++m) {
            const int rbase = brow + wm * 64 + m * 16 + kgrp * 4;
            f32x4 a = acc[m][n];
            #pragma unroll
            for (int q = 0; q < 4; ++q) {
                float sv = exp2f(a[q] * SCALE) + 1e-10f;
                S[(size_t)(rbase + q) * NN + col] = sv;
                cp += sv;
            }
        }
        atomicAdd(&colsum[wn * 64 + n * 16 + frow], cp);
    }
    __syncthreads();
    if (tid < BN) atomicAdd(&tcol[bcol + tid], colsum[tid]);
}

// ---------------- fp32 fallback Sinkhorn (small-ws path) -------------------
#define RROWS 8
__global__ __launch_bounds__(256) void row_pass_f32(
    const float* __restrict__ S, const float* __restrict__ t, float* __restrict__ u)
{
    __shared__ float vs[NN];
    __shared__ float red[RROWS][4];
    const int tid = threadIdx.x;
    const int wave = tid >> 6, lane = tid & 63;
    for (int i = tid; i < NN; i += 256) vs[i] = 1.0f / t[i];
    __syncthreads();
    const int row0 = blockIdx.x * RROWS;
    for (int rr = 0; rr < RROWS; ++rr) {
        const float4* rowp = (const float4*)(S + (size_t)(row0 + rr) * NN);
        float part = 0.f;
        #pragma unroll 4
        for (int c4 = tid; c4 < NN / 4; c4 += 256) {
            float4 sv = rowp[c4];
            float4 vv = ((const float4*)vs)[c4];
            part += sv.x * vv.x + sv.y * vv.y + sv.z * vv.z + sv.w * vv.w;
        }
        #pragma unroll
        for (int off = 32; off >= 1; off >>= 1) part += __shfl_down(part, off, 64);
        if (lane == 0) red[rr][wave] = part;
    }
    __syncthreads();
    if (tid < RROWS) {
        float rs = red[tid][0] + red[tid][1] + red[tid][2] + red[tid][3];
        u[row0 + tid] = 1.0f / rs;
    }
}

__global__ __launch_bounds__(256) void col_pass_f32(
    const float* __restrict__ S, const float* __restrict__ u, float* __restrict__ t)
{
    __shared__ float us[32];
    const int tid = threadIdx.x;
    const int cb = blockIdx.x & 3;
    const int rbk = blockIdx.x >> 2;
    const int col0 = cb * 1024 + tid * 4;
    const int row0 = rbk * 32;
    if (tid < 32) us[tid] = u[row0 + tid];
    __syncthreads();
    float a0 = 0, a1 = 0, a2 = 0, a3 = 0;
    #pragma unroll 8
    for (int r = 0; r < 32; ++r) {
        float4 sv = *(const float4*)(S + (size_t)(row0 + r) * NN + col0);
        float ur = us[r];
        a0 = fmaf(sv.x, ur, a0);
        a1 = fmaf(sv.y, ur, a1);
        a2 = fmaf(sv.z, ur, a2);
        a3 = fmaf(sv.w, ur, a3);
    }
    atomicAdd(&t[col0 + 0], a0);
    atomicAdd(&t[col0 + 1], a1);
    atomicAdd(&t[col0 + 2], a2);
    atomicAdd(&t[col0 + 3], a3);
}

__global__ __launch_bounds__(256) void final_f32_kernel(
    float* __restrict__ S, const float* __restrict__ t)
{
    __shared__ float vs[NN];
    const int tid = threadIdx.x;
    const int wave = tid >> 6, lane = tid & 63;
    for (int i = tid; i < NN; i += 256) vs[i] = 1.0f / t[i];
    __syncthreads();
    const int row0 = blockIdx.x * 8 + wave * 2;
    for (int rr = 0; rr < 2; ++rr) {
        float4* rowp = (float4*)(S + (size_t)(row0 + rr) * NN);
        float4 rv[16];
        #pragma unroll
        for (int ii = 0; ii < 16; ++ii) rv[ii] = rowp[lane + 64 * ii];
        float part = 0.f;
        #pragma unroll
        for (int ii = 0; ii < 16; ++ii) {
            float4 vv = ((const float4*)vs)[lane + 64 * ii];
            part += rv[ii].x * vv.x + rv[ii].y * vv.y + rv[ii].z * vv.z + rv[ii].w * vv.w;
        }
        #pragma unroll
        for (int off = 32; off >= 1; off >>= 1) part += __shfl_down(part, off, 64);
        part = __shfl(part, 0, 64);
        const float ui = 1.0f / part;
        #pragma unroll
        for (int ii = 0; ii < 16; ++ii) {
            int c4 = lane + 64 * ii;
            float4 vv = ((const float4*)vs)[c4];
            float4 o = rv[ii];
            o.x *= ui * vv.x;
            o.y *= ui * vv.y;
            o.z *= ui * vv.z;
            o.w *= ui * vv.w;
            rowp[c4] = o;
        }
    }
}

// ---------------------------------------------------------------------------
extern "C" void kernel_launch(void* const* d_in, const int* in_sizes, int n_in,
                              void* d_out, int out_size, void* d_ws, size_t ws_size,
                              hipStream_t stream)
{
    (void)in_sizes; (void)n_in; (void)out_size;
    const float* h0 = (const float*)d_in[0];
    const float* h1 = (const float*)d_in[1];
    const float* W1 = (const float*)d_in[2];
    const float* b1 = (const float*)d_in[3];
    const float* W2 = (const float*)d_in[4];
    const float* b2 = (const float*)d_in[5];
    float* S = (float*)d_out;

    // ---- workspace: Fhi/Flo (frag-major), Sb, u, t[5] ----
    char* ws = (char*)d_ws;
    const size_t FROW = (size_t)2 * NN * KP;          // 8192 x 320 elements
    const size_t FSZB = FROW * sizeof(unsigned short);
    unsigned short* Fhi = (unsigned short*)(ws);
    unsigned short* Flo = (unsigned short*)(ws + FSZB);
    const size_t SBSZ = (size_t)NN * NN * sizeof(unsigned short);
    const size_t TAILSZ = 6 * (size_t)NN * sizeof(float);
    const bool big = ws_size >= 2 * FSZB + SBSZ + TAILSZ;
    unsigned short* Sb = big ? (unsigned short*)(ws + 2 * FSZB) : nullptr;
    char* tail = ws + 2 * FSZB + (big ? SBSZ : 0);
    float* u = (float*)(tail);
    float* t = (float*)(tail + NN * sizeof(float));   // t[5] contiguous

    // ---- transient scratch inside d_out (dead until final writes S) ----
    unsigned short* usp = (unsigned short*)d_out;
    unsigned short* Hhi = usp;
    unsigned short* Hlo = usp + FROW;
    unsigned short* Yhi = usp + 2 * FROW;
    unsigned short* Ylo = usp + 3 * FROW;
    const size_t WSZ = (size_t)NPAD * KP;             // 384*320
    unsigned short* W1th = usp + 4 * FROW;
    unsigned short* W1tl = W1th + WSZ;
    unsigned short* W2th = W1tl + WSZ;
    unsigned short* W2tl = W2th + WSZ;
    char* zb = (char*)(W2tl + WSZ);
    float* Z      = (float*)zb;                       // 8192 x 320 fp32
    float* rowssq = (float*)(zb + FROW * sizeof(float));
    float* b1p    = rowssq + 2 * NN;
    float* b2p    = b1p + NPAD;
    float* tpart   = b2p + NPAD;                      // 16 x 4096 (gemm_exp256)
    float* colpart = tpart + 32 * NN;                 // 256 x 4096 (coop partials)

    prep_kernel<<<1147, 320, 0, stream>>>(h0, h1, W1, W2, b1, b2,
                                          Hhi, Hlo, W1th, W1tl, W2th, W2tl,
                                          b1p, b2p, rowssq);
    gemm_l1_kernel<<<192, 256, 0, stream>>>(Hhi, Hlo, W1th, W1tl, b1p, Yhi, Ylo);
    gemm_l2_kernel<<<192, 256, 0, stream>>>(Yhi, Ylo, W2th, W2tl, b2p, Z, rowssq);
    normalize_kernel<<<1024, 320, 0, stream>>>(Z, rowssq, Fhi, Flo);

    if (big) {
        gemm_exp256_kernel<<<256, 512, 0, stream>>>(Fhi, Flo, Sb, tpart);
        const unsigned short* Sb_c = Sb;
        const float* tpart_c = tpart;
        void* args[] = { (void*)&Sb_c, (void*)&tpart_c, (void*)&colpart,
                         (void*)&t, (void*)&S };
        (void)hipLaunchCooperativeKernel((void*)sinkhorn_coop_kernel,
                                         dim3(256), dim3(512), args, 0, stream);
    } else {
        hipMemsetAsync(t, 0, 5 * NN * sizeof(float), stream);
        gemm_exp_kernel<<<1024, 256, 0, stream>>>(Fhi, Flo, Fhi, Flo, S, t);
        for (int it = 0; it < 4; ++it) {
            row_pass_f32<<<512, 256, 0, stream>>>(S, t + it * NN, u);
            col_pass_f32<<<512, 256, 0, stream>>>(S, u, t + (it + 1) * NN);
        }
        final_f32_kernel<<<512, 256, 0, stream>>>(S, t + 4 * NN);
    }
}

// Round 14
// 212.995 us; speedup vs baseline: 4.0240x; 4.0240x over previous
//
#include <hip/hip_runtime.h>
#include <hip/hip_bf16.h>
#include <stdint.h>

#define NN 4096
#define EMB 300
#define KP  320           // padded K for all GEMMs
#define NKT 10            // KP / 32
#define NPAD 384          // padded N for MLP weight tiles (3 x 128)

typedef __attribute__((ext_vector_type(8))) short short8;
typedef __attribute__((ext_vector_type(4))) float f32x4;

__device__ __forceinline__ float bf2f(unsigned short b) {
    return __uint_as_float(((unsigned int)b) << 16);
}
__device__ __forceinline__ float bflo(unsigned int u) {
    return __uint_as_float(u << 16);
}
__device__ __forceinline__ float bfhi(unsigned int u) {
    return __uint_as_float(u & 0xFFFF0000u);
}
__device__ __forceinline__ void split_store(float f, unsigned short* hi, unsigned short* lo) {
    __hip_bfloat16 hb = __float2bfloat16(f);
    float hf = __bfloat162float(hb);
    __hip_bfloat16 lb = __float2bfloat16(f - hf);
    *hi = *reinterpret_cast<unsigned short*>(&hb);
    *lo = *reinterpret_cast<unsigned short*>(&lb);
}
__device__ __forceinline__ unsigned short f2bfu(float f) {
    __hip_bfloat16 hb = __float2bfloat16(f);
    return *reinterpret_cast<unsigned short*>(&hb);
}

// Fragment-major layout for a [rows x 320] MFMA operand:
//   element (rowblk*16 + frow, kt*32 + kgrp*8 + e)  lives at
//   ((rowblk*NKT + kt)*64 + kgrp*16 + frow)*8 + e
__device__ __forceinline__ size_t fidx(int rowblk, int kt, int frow, int kgrp, int e) {
    return ((size_t)(rowblk * NKT + kt) * 64 + kgrp * 16 + frow) * 8 + e;
}

// ---------------------------------------------------------------------------
// prep_kernel (vectorized): blocks 0..1023 split_h (8 rows x 40 chunks),
// 1024..1119 W transpose-split, 1120..1145 rowssq zero, 1146 bias pad.
// ---------------------------------------------------------------------------
__global__ __launch_bounds__(320) void prep_kernel(
    const float* __restrict__ h0, const float* __restrict__ h1,
    const float* __restrict__ W1, const float* __restrict__ W2,
    const float* __restrict__ b1, const float* __restrict__ b2,
    unsigned short* __restrict__ Hhi, unsigned short* __restrict__ Hlo,
    unsigned short* __restrict__ W1th, unsigned short* __restrict__ W1tl,
    unsigned short* __restrict__ W2th, unsigned short* __restrict__ W2tl,
    float* __restrict__ b1p, float* __restrict__ b2p, float* __restrict__ rowssq)
{
    const int blk = blockIdx.x;
    const int tid = threadIdx.x;
    if (blk < 1024) {
        const int r = tid / 40, c = tid % 40;     // 8 rows x 40 k-chunks
        const int row = blk * 8 + r;
        const float* hp = (row < NN) ? h0 + (size_t)row * EMB
                                     : h1 + (size_t)(row - NN) * EMB;
        float v[8];
        #pragma unroll
        for (int e = 0; e < 8; ++e) {
            int k = c * 8 + e;
            v[e] = (k < EMB) ? hp[k] : 0.f;
        }
        short8 hiv, lov;
        #pragma unroll
        for (int e = 0; e < 8; ++e) {
            unsigned short h_, l_;
            split_store(v[e], &h_, &l_);
            hiv[e] = (short)h_; lov[e] = (short)l_;
        }
        size_t o = fidx(row >> 4, c >> 2, row & 15, c & 3, 0);
        *(short8*)(Hhi + o) = hiv;
        *(short8*)(Hlo + o) = lov;
    } else if (blk < 1120) {
        const int wb = blk - 1024;                // 96 blocks x 8 n
        const int nn = tid / 40, c = tid % 40;
        const int n = wb * 8 + nn;                // 0..767
        const int which = (n >= NPAD);
        const int nl = which ? n - NPAD : n;      // 0..383
        const float* W = which ? W2 : W1;
        unsigned short* Wh = which ? W2th : W1th;
        unsigned short* Wl = which ? W2tl : W1tl;
        short8 hiv, lov;
        #pragma unroll
        for (int e = 0; e < 8; ++e) {
            int k = c * 8 + e;
            float val = (nl < EMB && k < EMB) ? W[(size_t)k * EMB + nl] : 0.f;
            unsigned short h_, l_;
            split_store(val, &h_, &l_);
            hiv[e] = (short)h_; lov[e] = (short)l_;
        }
        size_t o = fidx(nl >> 4, c >> 2, nl & 15, c & 3, 0);
        *(short8*)(Wh + o) = hiv;
        *(short8*)(Wl + o) = lov;
    } else if (blk < 1146) {
        int i = (blk - 1120) * 320 + tid;
        if (i < 2 * NN) rowssq[i] = 0.f;
    } else {
        for (int x = tid; x < NPAD; x += 320) {
            b1p[x] = (x < EMB) ? b1[x] : 0.f;
            b2p[x] = (x < EMB) ? b2[x] : 0.f;
        }
    }
}

// ---------------------------------------------------------------------------
// Barrier-free fragment GEMM core: 128x128 tile, 4 waves (2x2), split-bf16.
// ---------------------------------------------------------------------------
#define BM 128
#define BN 128

#define GEMM_FRAG_CORE(Ahi_, Alo_, Bhi_, Blo_, ARB0, BRB0)                     \
    const int tid  = threadIdx.x;                                              \
    const int wave = tid >> 6;                                                 \
    const int lane = tid & 63;                                                 \
    const int wm   = wave >> 1, wn = wave & 1;                                 \
    const int frow = lane & 15;                                                \
    const int kgrp = lane >> 4;                                                \
    (void)tid;                                                                 \
    f32x4 acc[4][4];                                                           \
    _Pragma("unroll")                                                          \
    for (int m = 0; m < 4; ++m)                                                \
        _Pragma("unroll")                                                      \
        for (int n = 0; n < 4; ++n) acc[m][n] = (f32x4)0.f;                    \
    const int arb = (ARB0) + wm * 4;                                           \
    const int brb = (BRB0) + wn * 4;                                           \
    const size_t lo8 = (size_t)lane * 8;                                       \
    _Pragma("unroll 2")                                                        \
    for (int kt = 0; kt < NKT; ++kt) {                                         \
        short8 ahi[4], alo[4], bhi[4], blo[4];                                 \
        _Pragma("unroll")                                                      \
        for (int m = 0; m < 4; ++m) {                                          \
            size_t b = (size_t)((arb + m) * NKT + kt) * 512 + lo8;             \
            ahi[m] = *(const short8*)(Ahi_ + b);                               \
            alo[m] = *(const short8*)(Alo_ + b);                               \
        }                                                                      \
        _Pragma("unroll")                                                      \
        for (int n = 0; n < 4; ++n) {                                          \
            size_t b = (size_t)((brb + n) * NKT + kt) * 512 + lo8;             \
            bhi[n] = *(const short8*)(Bhi_ + b);                               \
            blo[n] = *(const short8*)(Blo_ + b);                               \
        }                                                                      \
        _Pragma("unroll")                                                      \
        for (int m = 0; m < 4; ++m)                                            \
            _Pragma("unroll")                                                  \
            for (int n = 0; n < 4; ++n) {                                      \
                acc[m][n] = __builtin_amdgcn_mfma_f32_16x16x32_bf16(ahi[m], bhi[n], acc[m][n], 0, 0, 0); \
                acc[m][n] = __builtin_amdgcn_mfma_f32_16x16x32_bf16(ahi[m], blo[n], acc[m][n], 0, 0, 0); \
                acc[m][n] = __builtin_amdgcn_mfma_f32_16x16x32_bf16(alo[m], bhi[n], acc[m][n], 0, 0, 0); \
            }                                                                  \
    }

// ---------------------------------------------------------------------------
// gemm_l1: Y = split( relu( H @ W1 + b1 ) )  -> Y fragment-major
// ---------------------------------------------------------------------------
__global__ __launch_bounds__(256) void gemm_l1_kernel(
    const unsigned short* __restrict__ Ahi, const unsigned short* __restrict__ Alo,
    const unsigned short* __restrict__ Bhi, const unsigned short* __restrict__ Blo,
    const float* __restrict__ b1p,
    unsigned short* __restrict__ Yhi, unsigned short* __restrict__ Ylo)
{
    const int bx = blockIdx.x % 3;
    const int by = blockIdx.x / 3;
    const int brow = by * BM, bcol = bx * BN;
    GEMM_FRAG_CORE(Ahi, Alo, Bhi, Blo, by * 8, bx * 8)

    #pragma unroll
    for (int n = 0; n < 4; ++n) {
        const int col = bcol + wn * 64 + n * 16 + frow;
        const float bb = b1p[col];
        const bool ok = col < KP;
        #pragma unroll
        for (int m = 0; m < 4; ++m) {
            const int rbase = brow + wm * 64 + m * 16 + kgrp * 4;
            f32x4 a = acc[m][n];
            #pragma unroll
            for (int q = 0; q < 4; ++q) {
                if (ok) {
                    float y = fmaxf(a[q] + bb, 0.f);
                    int row = rbase + q;
                    size_t o = fidx(row >> 4, col >> 5, row & 15, (col >> 3) & 3, col & 7);
                    split_store(y, &Yhi[o], &Ylo[o]);
                }
            }
        }
    }
}

// ---------------------------------------------------------------------------
// gemm_l2: Z = Y @ W2 + b2 (fp32 row-major), rowssq[row] += sum_j Z^2
// ---------------------------------------------------------------------------
__global__ __launch_bounds__(256) void gemm_l2_kernel(
    const unsigned short* __restrict__ Ahi, const unsigned short* __restrict__ Alo,
    const unsigned short* __restrict__ Bhi, const unsigned short* __restrict__ Blo,
    const float* __restrict__ b2p,
    float* __restrict__ Z, float* __restrict__ rowssq)
{
    const int bx = blockIdx.x % 3;
    const int by = blockIdx.x / 3;
    const int brow = by * BM, bcol = bx * BN;
    GEMM_FRAG_CORE(Ahi, Alo, Bhi, Blo, by * 8, bx * 8)

    float sq[4][4];
    #pragma unroll
    for (int m = 0; m < 4; ++m)
        #pragma unroll
        for (int q = 0; q < 4; ++q) sq[m][q] = 0.f;

    #pragma unroll
    for (int n = 0; n < 4; ++n) {
        const int col = bcol + wn * 64 + n * 16 + frow;
        const float bb = b2p[col];
        const bool ok = col < KP;
        #pragma unroll
        for (int m = 0; m < 4; ++m) {
            const int rbase = brow + wm * 64 + m * 16 + kgrp * 4;
            f32x4 a = acc[m][n];
            #pragma unroll
            for (int q = 0; q < 4; ++q) {
                float z = a[q] + bb;
                if (ok) Z[(size_t)(rbase + q) * KP + col] = z;
                else    z = 0.f;
                sq[m][q] = fmaf(z, z, sq[m][q]);
            }
        }
    }
    #pragma unroll
    for (int m = 0; m < 4; ++m)
        #pragma unroll
        for (int q = 0; q < 4; ++q) {
            float v2 = sq[m][q];
            #pragma unroll
            for (int off = 1; off <= 8; off <<= 1) v2 += __shfl_xor(v2, off, 64);
            if ((lane & 15) == 0)
                atomicAdd(&rowssq[brow + wm * 64 + m * 16 + kgrp * 4 + q], v2);
        }
}

// ---------------------------------------------------------------------------
// normalize (vectorized): f = Z * rsqrt-row-norm -> Fhi/Flo fragment-major
// ---------------------------------------------------------------------------
__global__ __launch_bounds__(320) void normalize_kernel(
    const float* __restrict__ Z, const float* __restrict__ rowssq,
    unsigned short* __restrict__ Fhi, unsigned short* __restrict__ Flo)
{
    const int tid = threadIdx.x;
    const int r = tid / 40, c = tid % 40;
    const int row = blockIdx.x * 8 + r;
    const float sc = 1.0f / fmaxf(sqrtf(rowssq[row]), 1e-12f);
    const float* zp = Z + (size_t)row * KP + c * 8;
    short8 hiv, lov;
    #pragma unroll
    for (int e = 0; e < 8; ++e) {
        unsigned short h_, l_;
        split_store(zp[e] * sc, &h_, &l_);
        hiv[e] = (short)h_; lov[e] = (short)l_;
    }
    size_t o = fidx(row >> 4, c >> 2, row & 15, c & 3, 0);
    *(short8*)(Fhi + o) = hiv;
    *(short8*)(Flo + o) = lov;
}

// ---------------------------------------------------------------------------
// gemm_exp256: S0 = exp((f0 f1^T)/T)+eps, 256x256 tile, 8 waves (2x4).
// 2-D patch swizzle for per-XCD L2 residency.  (frozen from R10)
// ---------------------------------------------------------------------------
__global__ __launch_bounds__(512, 2) void gemm_exp256_kernel(
    const unsigned short* __restrict__ Fhi, const unsigned short* __restrict__ Flo,
    unsigned short* __restrict__ Sb, float* __restrict__ tpart)
{
    __shared__ unsigned short tile[128 * 256];
    __shared__ float colsum[256];

    const int p   = blockIdx.x & 7;
    const int idx = blockIdx.x >> 3;
    const int by  = (p >> 2) * 8 + (idx >> 2);
    const int bx  = (p & 3) * 4 + (idx & 3);
    const int brow = by * 256, bcol = bx * 256;

    const int tid  = threadIdx.x;
    const int wave = tid >> 6;
    const int lane = tid & 63;
    const int wm   = wave >> 2;
    const int wn   = wave & 3;
    const int frow = lane & 15;
    const int kgrp = lane >> 4;

    f32x4 acc[8][4];
    #pragma unroll
    for (int m = 0; m < 8; ++m)
        #pragma unroll
        for (int n = 0; n < 4; ++n) acc[m][n] = (f32x4)0.f;

    const int arb = by * 16 + wm * 8;
    const int brb = 256 + bx * 16 + wn * 4;
    const size_t lo8 = (size_t)lane * 8;

    for (int kt = 0; kt < NKT; ++kt) {
        short8 bhi[4], blo[4];
        #pragma unroll
        for (int n = 0; n < 4; ++n) {
            size_t b = (size_t)((brb + n) * NKT + kt) * 512 + lo8;
            bhi[n] = *(const short8*)(Fhi + b);
            blo[n] = *(const short8*)(Flo + b);
        }
        short8 ahi[8], alo[8];
        #pragma unroll
        for (int m = 0; m < 8; ++m) {
            size_t b = (size_t)((arb + m) * NKT + kt) * 512 + lo8;
            ahi[m] = *(const short8*)(Fhi + b);
            alo[m] = *(const short8*)(Flo + b);
        }
        #pragma unroll
        for (int m = 0; m < 8; ++m)
            #pragma unroll
            for (int n = 0; n < 4; ++n) {
                acc[m][n] = __builtin_amdgcn_mfma_f32_16x16x32_bf16(ahi[m], bhi[n], acc[m][n], 0, 0, 0);
                acc[m][n] = __builtin_amdgcn_mfma_f32_16x16x32_bf16(ahi[m], blo[n], acc[m][n], 0, 0, 0);
                acc[m][n] = __builtin_amdgcn_mfma_f32_16x16x32_bf16(alo[m], bhi[n], acc[m][n], 0, 0, 0);
            }
    }

    const float SCALE = 36.067376022224085f;
    if (tid < 256) colsum[tid] = 0.f;
    __syncthreads();

    for (int pass = 0; pass < 2; ++pass) {
        if (wm == pass) {
            #pragma unroll
            for (int n = 0; n < 4; ++n) {
                const int cl = wn * 64 + n * 16 + frow;
                float cp = 0.f;
                #pragma unroll
                for (int m = 0; m < 8; ++m) {
                    const int rl = m * 16 + kgrp * 4;
                    f32x4 a = acc[m][n];
                    #pragma unroll
                    for (int q = 0; q < 4; ++q) {
                        float sv = exp2f(a[q] * SCALE) + 1e-10f;
                        cp += sv;
                        tile[(rl + q) * 256 + cl] = f2bfu(sv);
                    }
                }
                atomicAdd(&colsum[cl], cp);
            }
        }
        __syncthreads();
        const int rbase = brow + pass * 128;
        for (int i = tid; i < 128 * 256 / 8; i += 512) {
            int row = i >> 5, ch = i & 31;
            *(short8*)(Sb + (size_t)(rbase + row) * NN + bcol + ch * 8) =
                *(const short8*)(tile + row * 256 + ch * 8);
        }
        __syncthreads();
    }
    if (tid < 256) tpart[(size_t)by * NN + bcol + tid] = colsum[tid];
}

// ---------------------------------------------------------------------------
// fallback gemm_exp (fp32 S, atomic colsums) for small-ws path
// ---------------------------------------------------------------------------
__global__ __launch_bounds__(256) void gemm_exp_kernel(
    const unsigned short* __restrict__ Ahi, const unsigned short* __restrict__ Alo,
    const unsigned short* __restrict__ Bhi, const unsigned short* __restrict__ Blo,
    float* __restrict__ S, float* __restrict__ tcol)
{
    __shared__ float colsum[BN];
    const int bx = blockIdx.x & 31;
    const int by = blockIdx.x >> 5;
    const int brow = by * BM, bcol = bx * BN;
    GEMM_FRAG_CORE(Ahi, Alo, Bhi, Blo, by * 8, 256 + bx * 8)

    const float SCALE = 36.067376022224085f;
    if (tid < BN) colsum[tid] = 0.f;
    __syncthreads();
    #pragma unroll
    for (int n = 0; n < 4; ++n) {
        const int col = bcol + wn * 64 + n * 16 + frow;
        float cp = 0.f;
        #pragma unroll
        for (int m = 0; m < 4; ++m) {
            const int rbase = brow + wm * 64 + m * 16 + kgrp * 4;
            f32x4 a = acc[m][n];
            #pragma unroll
            for (int q = 0; q < 4; ++q) {
                float sv = exp2f(a[q] * SCALE) + 1e-10f;
                S[(size_t)(rbase + q) * NN + col] = sv;
                cp += sv;
            }
        }
        atomicAdd(&colsum[wn * 64 + n * 16 + frow], cp);
    }
    __syncthreads();
    if (tid < BN) atomicAdd(&tcol[bcol + tid], colsum[tid]);
}

// ---------------------------------------------------------------------------
// reduce_part: dst[col] = sum_{k<np} part[k*NN + col]   (grid 16 x 256)
// ---------------------------------------------------------------------------
__global__ __launch_bounds__(256) void reduce_part_kernel(
    const float* __restrict__ part, float* __restrict__ dst, int np)
{
    const int col = blockIdx.x * 256 + threadIdx.x;
    float a0 = 0.f, a1 = 0.f, a2 = 0.f, a3 = 0.f;
    int k = 0;
    for (; k + 3 < np; k += 4) {
        a0 += part[(size_t)k * NN + col];
        a1 += part[(size_t)(k + 1) * NN + col];
        a2 += part[(size_t)(k + 2) * NN + col];
        a3 += part[(size_t)(k + 3) * NN + col];
    }
    for (; k < np; ++k) a0 += part[(size_t)k * NN + col];
    dst[col] = (a0 + a1) + (a2 + a3);
}

// reduce 256-deep partials: 64 blocks x 256 thr
__global__ __launch_bounds__(256) void reduce256_kernel(
    const float* __restrict__ part, float* __restrict__ dst)
{
    __shared__ float red[4][64];
    const int tid = threadIdx.x;
    const int col = blockIdx.x * 64 + (tid & 63);
    const int grp = tid >> 6;
    float s = 0.f;
    #pragma unroll 4
    for (int k = grp * 64; k < grp * 64 + 64; ++k)
        s += part[(size_t)k * NN + col];
    red[grp][tid & 63] = s;
    __syncthreads();
    if (tid < 64)
        dst[col] = (red[0][tid] + red[1][tid]) + (red[2][tid] + red[3][tid]);
}

// ---------------------------------------------------------------------------
// fused_pass: one Sinkhorn (row,col) pair, stripe held in REGISTERS.
// 256 blocks x 512 threads; block owns 16 rows; thread holds 16 uint4.
// ---------------------------------------------------------------------------
__global__ __launch_bounds__(512, 2) void fused_pass_b16(
    const unsigned short* __restrict__ Sb, const float* __restrict__ t,
    float* __restrict__ part)
{
    __shared__ float vs[NN];
    __shared__ float red[16][8];
    __shared__ float us[16];
    const int tid = threadIdx.x;
    const int wave = tid >> 6, lane = tid & 63;
    for (int i = tid; i < NN / 4; i += 512) {
        float4 tv = ((const float4*)t)[i];
        float4 vv;
        vv.x = 1.0f / tv.x; vv.y = 1.0f / tv.y;
        vv.z = 1.0f / tv.z; vv.w = 1.0f / tv.w;
        ((float4*)vs)[i] = vv;
    }
    __syncthreads();
    const float4* vs4 = (const float4*)vs;
    const float4 va = vs4[tid * 2], vb = vs4[tid * 2 + 1];
    const int row0 = blockIdx.x * 16;

    uint4 rv[16];
    #pragma unroll
    for (int r = 0; r < 16; ++r) {
        rv[r] = *(const uint4*)(Sb + (size_t)(row0 + r) * NN + tid * 8);
        float p = 0.f;
        p = fmaf(bflo(rv[r].x), va.x, p);
        p = fmaf(bfhi(rv[r].x), va.y, p);
        p = fmaf(bflo(rv[r].y), va.z, p);
        p = fmaf(bfhi(rv[r].y), va.w, p);
        p = fmaf(bflo(rv[r].z), vb.x, p);
        p = fmaf(bfhi(rv[r].z), vb.y, p);
        p = fmaf(bflo(rv[r].w), vb.z, p);
        p = fmaf(bfhi(rv[r].w), vb.w, p);
        #pragma unroll
        for (int off = 32; off >= 1; off >>= 1) p += __shfl_down(p, off, 64);
        if (lane == 0) red[r][wave] = p;
    }
    __syncthreads();
    if (tid < 16) {
        float s = 0.f;
        #pragma unroll
        for (int w = 0; w < 8; ++w) s += red[tid][w];
        us[tid] = 1.0f / s;
    }
    __syncthreads();

    float a[8];
    #pragma unroll
    for (int e = 0; e < 8; ++e) a[e] = 0.f;
    #pragma unroll
    for (int r = 0; r < 16; ++r) {
        const float ur = us[r];
        a[0] = fmaf(bflo(rv[r].x), ur, a[0]);
        a[1] = fmaf(bfhi(rv[r].x), ur, a[1]);
        a[2] = fmaf(bflo(rv[r].y), ur, a[2]);
        a[3] = fmaf(bfhi(rv[r].y), ur, a[3]);
        a[4] = fmaf(bflo(rv[r].z), ur, a[4]);
        a[5] = fmaf(bfhi(rv[r].z), ur, a[5]);
        a[6] = fmaf(bflo(rv[r].w), ur, a[6]);
        a[7] = fmaf(bfhi(rv[r].w), ur, a[7]);
    }
    float* pp = part + (size_t)blockIdx.x * NN + tid * 8;
    *(float4*)(pp)     = make_float4(a[0], a[1], a[2], a[3]);
    *(float4*)(pp + 4) = make_float4(a[4], a[5], a[6], a[7]);
}

// ---------------------------------------------------------------------------
// final512: u_i = 1/(Sb_i . v); Out = u_i * Sb_ij * v_j.  Same stripe-in-
// registers structure as fused_pass (proven), output write instead of partials.
// ---------------------------------------------------------------------------
__global__ __launch_bounds__(512, 2) void final512_kernel(
    const unsigned short* __restrict__ Sb, const float* __restrict__ t,
    float* __restrict__ Out)
{
    __shared__ float vs[NN];
    __shared__ float red[16][8];
    __shared__ float us[16];
    const int tid = threadIdx.x;
    const int wave = tid >> 6, lane = tid & 63;
    for (int i = tid; i < NN / 4; i += 512) {
        float4 tv = ((const float4*)t)[i];
        float4 vv;
        vv.x = 1.0f / tv.x; vv.y = 1.0f / tv.y;
        vv.z = 1.0f / tv.z; vv.w = 1.0f / tv.w;
        ((float4*)vs)[i] = vv;
    }
    __syncthreads();
    const float4* vs4 = (const float4*)vs;
    const float4 va = vs4[tid * 2], vb = vs4[tid * 2 + 1];
    const int row0 = blockIdx.x * 16;

    uint4 rv[16];
    #pragma unroll
    for (int r = 0; r < 16; ++r) {
        rv[r] = *(const uint4*)(Sb + (size_t)(row0 + r) * NN + tid * 8);
        float p = 0.f;
        p = fmaf(bflo(rv[r].x), va.x, p);
        p = fmaf(bfhi(rv[r].x), va.y, p);
        p = fmaf(bflo(rv[r].y), va.z, p);
        p = fmaf(bfhi(rv[r].y), va.w, p);
        p = fmaf(bflo(rv[r].z), vb.x, p);
        p = fmaf(bfhi(rv[r].z), vb.y, p);
        p = fmaf(bflo(rv[r].w), vb.z, p);
        p = fmaf(bfhi(rv[r].w), vb.w, p);
        #pragma unroll
        for (int off = 32; off >= 1; off >>= 1) p += __shfl_down(p, off, 64);
        if (lane == 0) red[r][wave] = p;
    }
    __syncthreads();
    if (tid < 16) {
        float s = 0.f;
        #pragma unroll
        for (int w = 0; w < 8; ++w) s += red[tid][w];
        us[tid] = 1.0f / s;
    }
    __syncthreads();

    #pragma unroll
    for (int r = 0; r < 16; ++r) {
        const float ui = us[r];
        float* outp = Out + (size_t)(row0 + r) * NN + tid * 8;
        float4 o0, o1;
        o0.x = bflo(rv[r].x) * ui * va.x;
        o0.y = bfhi(rv[r].x) * ui * va.y;
        o0.z = bflo(rv[r].y) * ui * va.z;
        o0.w = bfhi(rv[r].y) * ui * va.w;
        o1.x = bflo(rv[r].z) * ui * vb.x;
        o1.y = bfhi(rv[r].z) * ui * vb.y;
        o1.z = bflo(rv[r].w) * ui * vb.z;
        o1.w = bfhi(rv[r].w) * ui * vb.w;
        *(float4*)(outp)     = o0;
        *(float4*)(outp + 4) = o1;
    }
}

// ---------------- fp32 fallback Sinkhorn (small-ws path) -------------------
#define RROWS 8
__global__ __launch_bounds__(256) void row_pass_f32(
    const float* __restrict__ S, const float* __restrict__ t, float* __restrict__ u)
{
    __shared__ float vs[NN];
    __shared__ float red[RROWS][4];
    const int tid = threadIdx.x;
    const int wave = tid >> 6, lane = tid & 63;
    for (int i = tid; i < NN; i += 256) vs[i] = 1.0f / t[i];
    __syncthreads();
    const int row0 = blockIdx.x * RROWS;
    for (int rr = 0; rr < RROWS; ++rr) {
        const float4* rowp = (const float4*)(S + (size_t)(row0 + rr) * NN);
        float part = 0.f;
        #pragma unroll 4
        for (int c4 = tid; c4 < NN / 4; c4 += 256) {
            float4 sv = rowp[c4];
            float4 vv = ((const float4*)vs)[c4];
            part += sv.x * vv.x + sv.y * vv.y + sv.z * vv.z + sv.w * vv.w;
        }
        #pragma unroll
        for (int off = 32; off >= 1; off >>= 1) part += __shfl_down(part, off, 64);
        if (lane == 0) red[rr][wave] = part;
    }
    __syncthreads();
    if (tid < RROWS) {
        float rs = red[tid][0] + red[tid][1] + red[tid][2] + red[tid][3];
        u[row0 + tid] = 1.0f / rs;
    }
}

__global__ __launch_bounds__(256) void col_pass_f32(
    const float* __restrict__ S, const float* __restrict__ u, float* __restrict__ t)
{
    __shared__ float us[32];
    const int tid = threadIdx.x;
    const int cb = blockIdx.x & 3;
    const int rbk = blockIdx.x >> 2;
    const int col0 = cb * 1024 + tid * 4;
    const int row0 = rbk * 32;
    if (tid < 32) us[tid] = u[row0 + tid];
    __syncthreads();
    float a0 = 0, a1 = 0, a2 = 0, a3 = 0;
    #pragma unroll 8
    for (int r = 0; r < 32; ++r) {
        float4 sv = *(const float4*)(S + (size_t)(row0 + r) * NN + col0);
        float ur = us[r];
        a0 = fmaf(sv.x, ur, a0);
        a1 = fmaf(sv.y, ur, a1);
        a2 = fmaf(sv.z, ur, a2);
        a3 = fmaf(sv.w, ur, a3);
    }
    atomicAdd(&t[col0 + 0], a0);
    atomicAdd(&t[col0 + 1], a1);
    atomicAdd(&t[col0 + 2], a2);
    atomicAdd(&t[col0 + 3], a3);
}

__global__ __launch_bounds__(256) void final_f32_kernel(
    float* __restrict__ S, const float* __restrict__ t)
{
    __shared__ float vs[NN];
    const int tid = threadIdx.x;
    const int wave = tid >> 6, lane = tid & 63;
    for (int i = tid; i < NN; i += 256) vs[i] = 1.0f / t[i];
    __syncthreads();
    const int row0 = blockIdx.x * 8 + wave * 2;
    for (int rr = 0; rr < 2; ++rr) {
        float4* rowp = (float4*)(S + (size_t)(row0 + rr) * NN);
        float4 rv[16];
        #pragma unroll
        for (int ii = 0; ii < 16; ++ii) rv[ii] = rowp[lane + 64 * ii];
        float part = 0.f;
        #pragma unroll
        for (int ii = 0; ii < 16; ++ii) {
            float4 vv = ((const float4*)vs)[lane + 64 * ii];
            part += rv[ii].x * vv.x + rv[ii].y * vv.y + rv[ii].z * vv.z + rv[ii].w * vv.w;
        }
        #pragma unroll
        for (int off = 32; off >= 1; off >>= 1) part += __shfl_down(part, off, 64);
        part = __shfl(part, 0, 64);
        const float ui = 1.0f / part;
        #pragma unroll
        for (int ii = 0; ii < 16; ++ii) {
            int c4 = lane + 64 * ii;
            float4 vv = ((const float4*)vs)[c4];
            float4 o = rv[ii];
            o.x *= ui * vv.x;
            o.y *= ui * vv.y;
            o.z *= ui * vv.z;
            o.w *= ui * vv.w;
            rowp[c4] = o;
        }
    }
}

// ---------------------------------------------------------------------------
extern "C" void kernel_launch(void* const* d_in, const int* in_sizes, int n_in,
                              void* d_out, int out_size, void* d_ws, size_t ws_size,
                              hipStream_t stream)
{
    (void)in_sizes; (void)n_in; (void)out_size;
    const float* h0 = (const float*)d_in[0];
    const float* h1 = (const float*)d_in[1];
    const float* W1 = (const float*)d_in[2];
    const float* b1 = (const float*)d_in[3];
    const float* W2 = (const float*)d_in[4];
    const float* b2 = (const float*)d_in[5];
    float* S = (float*)d_out;

    // ---- workspace: Fhi/Flo (frag-major), Sb, u, t[5] ----
    char* ws = (char*)d_ws;
    const size_t FROW = (size_t)2 * NN * KP;          // 8192 x 320 elements
    const size_t FSZB = FROW * sizeof(unsigned short);
    unsigned short* Fhi = (unsigned short*)(ws);
    unsigned short* Flo = (unsigned short*)(ws + FSZB);
    const size_t SBSZ = (size_t)NN * NN * sizeof(unsigned short);
    const size_t TAILSZ = 6 * (size_t)NN * sizeof(float);
    const bool big = ws_size >= 2 * FSZB + SBSZ + TAILSZ;
    unsigned short* Sb = big ? (unsigned short*)(ws + 2 * FSZB) : nullptr;
    char* tail = ws + 2 * FSZB + (big ? SBSZ : 0);
    float* u = (float*)(tail);
    float* t = (float*)(tail + NN * sizeof(float));   // t[5] contiguous

    // ---- transient scratch inside d_out (dead until final writes S) ----
    unsigned short* usp = (unsigned short*)d_out;
    unsigned short* Hhi = usp;
    unsigned short* Hlo = usp + FROW;
    unsigned short* Yhi = usp + 2 * FROW;
    unsigned short* Ylo = usp + 3 * FROW;
    const size_t WSZ = (size_t)NPAD * KP;             // 384*320
    unsigned short* W1th = usp + 4 * FROW;
    unsigned short* W1tl = W1th + WSZ;
    unsigned short* W2th = W1tl + WSZ;
    unsigned short* W2tl = W2th + WSZ;
    char* zb = (char*)(W2tl + WSZ);
    float* Z      = (float*)zb;                       // 8192 x 320 fp32
    float* rowssq = (float*)(zb + FROW * sizeof(float));
    float* b1p    = rowssq + 2 * NN;
    float* b2p    = b1p + NPAD;
    float* tpart   = b2p + NPAD;                      // 16 x 4096 (gemm_exp256)
    float* colpart = tpart + 32 * NN;                 // 256 x 4096 (fused passes)

    prep_kernel<<<1147, 320, 0, stream>>>(h0, h1, W1, W2, b1, b2,
                                          Hhi, Hlo, W1th, W1tl, W2th, W2tl,
                                          b1p, b2p, rowssq);
    gemm_l1_kernel<<<192, 256, 0, stream>>>(Hhi, Hlo, W1th, W1tl, b1p, Yhi, Ylo);
    gemm_l2_kernel<<<192, 256, 0, stream>>>(Yhi, Ylo, W2th, W2tl, b2p, Z, rowssq);
    normalize_kernel<<<1024, 320, 0, stream>>>(Z, rowssq, Fhi, Flo);

    if (big) {
        gemm_exp256_kernel<<<256, 512, 0, stream>>>(Fhi, Flo, Sb, tpart);
        reduce_part_kernel<<<16, 256, 0, stream>>>(tpart, t, 16);       // t[0]
        for (int it = 0; it < 4; ++it) {                                // i = 1..8
            fused_pass_b16<<<256, 512, 0, stream>>>(Sb, t + it * NN, colpart);
            reduce256_kernel<<<64, 256, 0, stream>>>(colpart, t + (it + 1) * NN);
        }
        final512_kernel<<<256, 512, 0, stream>>>(Sb, t + 4 * NN, S);    // i=9 + out
    } else {
        hipMemsetAsync(t, 0, 5 * NN * sizeof(float), stream);
        gemm_exp_kernel<<<1024, 256, 0, stream>>>(Fhi, Flo, Fhi, Flo, S, t);
        for (int it = 0; it < 4; ++it) {
            row_pass_f32<<<512, 256, 0, stream>>>(S, t + it * NN, u);
            col_pass_f32<<<512, 256, 0, stream>>>(S, u, t + (it + 1) * NN);
        }
        final_f32_kernel<<<512, 256, 0, stream>>>(S, t + 4 * NN);
    }
}

// Round 15
// 208.042 us; speedup vs baseline: 4.1197x; 1.0238x over previous
//
#include <hip/hip_runtime.h>
#include <hip/hip_bf16.h>
#include <stdint.h>

#define NN 4096
#define EMB 300
#define KP  320           // padded K for all GEMMs
#define NKT 10            // KP / 32
#define NPAD 384          // padded N for MLP weight tiles (3 x 128)

typedef __attribute__((ext_vector_type(8))) short short8;
typedef __attribute__((ext_vector_type(4))) float f32x4;

__device__ __forceinline__ float bf2f(unsigned short b) {
    return __uint_as_float(((unsigned int)b) << 16);
}
__device__ __forceinline__ float bflo(unsigned int u) {
    return __uint_as_float(u << 16);
}
__device__ __forceinline__ float bfhi(unsigned int u) {
    return __uint_as_float(u & 0xFFFF0000u);
}
__device__ __forceinline__ void split_store(float f, unsigned short* hi, unsigned short* lo) {
    __hip_bfloat16 hb = __float2bfloat16(f);
    float hf = __bfloat162float(hb);
    __hip_bfloat16 lb = __float2bfloat16(f - hf);
    *hi = *reinterpret_cast<unsigned short*>(&hb);
    *lo = *reinterpret_cast<unsigned short*>(&lb);
}
__device__ __forceinline__ unsigned short f2bfu(float f) {
    __hip_bfloat16 hb = __float2bfloat16(f);
    return *reinterpret_cast<unsigned short*>(&hb);
}

// Fragment-major layout for a [rows x 320] MFMA operand:
//   element (rowblk*16 + frow, kt*32 + kgrp*8 + e)  lives at
//   ((rowblk*NKT + kt)*64 + kgrp*16 + frow)*8 + e
__device__ __forceinline__ size_t fidx(int rowblk, int kt, int frow, int kgrp, int e) {
    return ((size_t)(rowblk * NKT + kt) * 64 + kgrp * 16 + frow) * 8 + e;
}

// ---------------------------------------------------------------------------
// prep_kernel: wave-per-tile (lane = kg*16+frow -> coalesced 1KB tile writes)
// widx 0..5119: split_h tiles; 5120..5599: W transpose-split tiles;
// blocks 1400..1431: rowssq zero; block 1432: bias pad.
// ---------------------------------------------------------------------------
__global__ __launch_bounds__(256) void prep_kernel(
    const float* __restrict__ h0, const float* __restrict__ h1,
    const float* __restrict__ W1, const float* __restrict__ W2,
    const float* __restrict__ b1, const float* __restrict__ b2,
    unsigned short* __restrict__ Hhi, unsigned short* __restrict__ Hlo,
    unsigned short* __restrict__ W1th, unsigned short* __restrict__ W1tl,
    unsigned short* __restrict__ W2th, unsigned short* __restrict__ W2tl,
    float* __restrict__ b1p, float* __restrict__ b2p, float* __restrict__ rowssq)
{
    const int blk = blockIdx.x;
    const int tid = threadIdx.x;
    const int wave = tid >> 6, lane = tid & 63;
    const int kg = lane >> 4, frow = lane & 15;
    const int widx = blk * 4 + wave;

    if (widx < 5120) {                       // split_h: rowblk 0..511, kt 0..9
        const int rowblk = widx / 10, kt = widx - rowblk * 10;
        const int row = rowblk * 16 + frow;
        const float* hp = (row < NN) ? h0 + (size_t)row * EMB
                                     : h1 + (size_t)(row - NN) * EMB;
        const int c0 = kt * 32 + kg * 8;
        short8 hiv, lov;
        #pragma unroll
        for (int e = 0; e < 8; ++e) {
            float v = (c0 + e < EMB) ? hp[c0 + e] : 0.f;
            unsigned short h_, l_;
            split_store(v, &h_, &l_);
            hiv[e] = (short)h_; lov[e] = (short)l_;
        }
        size_t o = (size_t)widx * 512 + lane * 8;   // (rowblk*NKT+kt)*512
        *(short8*)(Hhi + o) = hiv;
        *(short8*)(Hlo + o) = lov;
    } else if (widx < 5600) {                // W tiles: nblk 0..47, kt 0..9
        const int w2 = widx - 5120;
        const int nblk = w2 / 10, kt = w2 - nblk * 10;
        const int which = nblk >= 24;
        const int nb = nblk - which * 24;    // 0..23
        const int nl = nb * 16 + frow;       // 0..383
        const float* W = which ? W2 : W1;
        unsigned short* Wh = which ? W2th : W1th;
        unsigned short* Wl = which ? W2tl : W1tl;
        const int k0 = kt * 32 + kg * 8;
        short8 hiv, lov;
        #pragma unroll
        for (int e = 0; e < 8; ++e) {
            int k = k0 + e;
            float v = (nl < EMB && k < EMB) ? W[(size_t)k * EMB + nl] : 0.f;
            unsigned short h_, l_;
            split_store(v, &h_, &l_);
            hiv[e] = (short)h_; lov[e] = (short)l_;
        }
        size_t o = (size_t)(nb * NKT + kt) * 512 + lane * 8;
        *(short8*)(Wh + o) = hiv;
        *(short8*)(Wl + o) = lov;
    } else if (blk >= 1400 && blk < 1432) {
        int i = (blk - 1400) * 256 + tid;    // exactly 2*NN = 8192
        rowssq[i] = 0.f;
    } else if (blk == 1432) {
        for (int x = tid; x < NPAD; x += 256) {
            b1p[x] = (x < EMB) ? b1[x] : 0.f;
            b2p[x] = (x < EMB) ? b2[x] : 0.f;
        }
    }
}

// ---------------------------------------------------------------------------
// Barrier-free fragment GEMM core: 128x128 tile, 4 waves (2x2), split-bf16.
// ---------------------------------------------------------------------------
#define BM 128
#define BN 128

#define GEMM_FRAG_CORE(Ahi_, Alo_, Bhi_, Blo_, ARB0, BRB0)                     \
    const int tid  = threadIdx.x;                                              \
    const int wave = tid >> 6;                                                 \
    const int lane = tid & 63;                                                 \
    const int wm   = wave >> 1, wn = wave & 1;                                 \
    const int frow = lane & 15;                                                \
    const int kgrp = lane >> 4;                                                \
    (void)tid;                                                                 \
    f32x4 acc[4][4];                                                           \
    _Pragma("unroll")                                                          \
    for (int m = 0; m < 4; ++m)                                                \
        _Pragma("unroll")                                                      \
        for (int n = 0; n < 4; ++n) acc[m][n] = (f32x4)0.f;                    \
    const int arb = (ARB0) + wm * 4;                                           \
    const int brb = (BRB0) + wn * 4;                                           \
    const size_t lo8 = (size_t)lane * 8;                                       \
    _Pragma("unroll 2")                                                        \
    for (int kt = 0; kt < NKT; ++kt) {                                         \
        short8 ahi[4], alo[4], bhi[4], blo[4];                                 \
        _Pragma("unroll")                                                      \
        for (int m = 0; m < 4; ++m) {                                          \
            size_t b = (size_t)((arb + m) * NKT + kt) * 512 + lo8;             \
            ahi[m] = *(const short8*)(Ahi_ + b);                               \
            alo[m] = *(const short8*)(Alo_ + b);                               \
        }                                                                      \
        _Pragma("unroll")                                                      \
        for (int n = 0; n < 4; ++n) {                                          \
            size_t b = (size_t)((brb + n) * NKT + kt) * 512 + lo8;             \
            bhi[n] = *(const short8*)(Bhi_ + b);                               \
            blo[n] = *(const short8*)(Blo_ + b);                               \
        }                                                                      \
        _Pragma("unroll")                                                      \
        for (int m = 0; m < 4; ++m)                                            \
            _Pragma("unroll")                                                  \
            for (int n = 0; n < 4; ++n) {                                      \
                acc[m][n] = __builtin_amdgcn_mfma_f32_16x16x32_bf16(ahi[m], bhi[n], acc[m][n], 0, 0, 0); \
                acc[m][n] = __builtin_amdgcn_mfma_f32_16x16x32_bf16(ahi[m], blo[n], acc[m][n], 0, 0, 0); \
                acc[m][n] = __builtin_amdgcn_mfma_f32_16x16x32_bf16(alo[m], bhi[n], acc[m][n], 0, 0, 0); \
            }                                                                  \
    }

// ---------------------------------------------------------------------------
// gemm_l1: Y = split( relu( H @ W1 + b1 ) )  -> Y fragment-major.
// Epilogue: LDS staging (padded rows) + coalesced frag-major writeout.
// ---------------------------------------------------------------------------
#define LP 136   // padded LDS row (ushorts): bank-stride 4 on 256B-stride reads
__global__ __launch_bounds__(256) void gemm_l1_kernel(
    const unsigned short* __restrict__ Ahi, const unsigned short* __restrict__ Alo,
    const unsigned short* __restrict__ Bhi, const unsigned short* __restrict__ Blo,
    const float* __restrict__ b1p,
    unsigned short* __restrict__ Yhi, unsigned short* __restrict__ Ylo)
{
    __shared__ unsigned short lYhi[128 * LP];
    __shared__ unsigned short lYlo[128 * LP];
    const int bx = blockIdx.x % 3;
    const int by = blockIdx.x / 3;
    const int brow = by * BM, bcol = bx * BN;
    (void)brow;
    GEMM_FRAG_CORE(Ahi, Alo, Bhi, Blo, by * 8, bx * 8)

    #pragma unroll
    for (int n = 0; n < 4; ++n) {
        const int cl = wn * 64 + n * 16 + frow;
        const float bb = b1p[bcol + cl];
        #pragma unroll
        for (int m = 0; m < 4; ++m) {
            const int rl = wm * 64 + m * 16 + kgrp * 4;
            f32x4 a = acc[m][n];
            #pragma unroll
            for (int q = 0; q < 4; ++q) {
                float y = fmaxf(a[q] + bb, 0.f);
                unsigned short h_, l_;
                split_store(y, &h_, &l_);
                lYhi[(rl + q) * LP + cl] = h_;
                lYlo[(rl + q) * LP + cl] = l_;
            }
        }
    }
    __syncthreads();

    const int rbB = by * 8;          // global rowblk base
    const int ktB = bx * 4;          // global kt base
    for (int i = tid; i < 32 * 64; i += 256) {
        const int t = i >> 6, l = i & 63;
        const int rb = t >> 2, ktc = t & 3;
        const int gkt = ktB + ktc;
        if (gkt >= NKT) continue;                  // skip K-pad tiles
        const int row_l = rb * 16 + (l & 15);
        const int col_l = ktc * 32 + (l >> 4) * 8;
        size_t o = (size_t)((rbB + rb) * NKT + gkt) * 512 + l * 8;
        *(short8*)(Yhi + o) = *(const short8*)(lYhi + row_l * LP + col_l);
        *(short8*)(Ylo + o) = *(const short8*)(lYlo + row_l * LP + col_l);
    }
}

// ---------------------------------------------------------------------------
// gemm_l2: Z = Y @ W2 + b2 (fp32 row-major), rowssq[row] += sum_j Z^2
// ---------------------------------------------------------------------------
__global__ __launch_bounds__(256) void gemm_l2_kernel(
    const unsigned short* __restrict__ Ahi, const unsigned short* __restrict__ Alo,
    const unsigned short* __restrict__ Bhi, const unsigned short* __restrict__ Blo,
    const float* __restrict__ b2p,
    float* __restrict__ Z, float* __restrict__ rowssq)
{
    const int bx = blockIdx.x % 3;
    const int by = blockIdx.x / 3;
    const int brow = by * BM, bcol = bx * BN;
    GEMM_FRAG_CORE(Ahi, Alo, Bhi, Blo, by * 8, bx * 8)

    float sq[4][4];
    #pragma unroll
    for (int m = 0; m < 4; ++m)
        #pragma unroll
        for (int q = 0; q < 4; ++q) sq[m][q] = 0.f;

    #pragma unroll
    for (int n = 0; n < 4; ++n) {
        const int col = bcol + wn * 64 + n * 16 + frow;
        const float bb = b2p[col];
        const bool ok = col < KP;
        #pragma unroll
        for (int m = 0; m < 4; ++m) {
            const int rbase = brow + wm * 64 + m * 16 + kgrp * 4;
            f32x4 a = acc[m][n];
            #pragma unroll
            for (int q = 0; q < 4; ++q) {
                float z = a[q] + bb;
                if (ok) Z[(size_t)(rbase + q) * KP + col] = z;
                else    z = 0.f;
                sq[m][q] = fmaf(z, z, sq[m][q]);
            }
        }
    }
    #pragma unroll
    for (int m = 0; m < 4; ++m)
        #pragma unroll
        for (int q = 0; q < 4; ++q) {
            float v2 = sq[m][q];
            #pragma unroll
            for (int off = 1; off <= 8; off <<= 1) v2 += __shfl_xor(v2, off, 64);
            if ((lane & 15) == 0)
                atomicAdd(&rowssq[brow + wm * 64 + m * 16 + kgrp * 4 + q], v2);
        }
}

// ---------------------------------------------------------------------------
// normalize: wave-per-tile, coalesced frag-major writes.
// ---------------------------------------------------------------------------
__global__ __launch_bounds__(256) void normalize_kernel(
    const float* __restrict__ Z, const float* __restrict__ rowssq,
    unsigned short* __restrict__ Fhi, unsigned short* __restrict__ Flo)
{
    const int tid = threadIdx.x;
    const int wave = tid >> 6, lane = tid & 63;
    const int kg = lane >> 4, frow = lane & 15;
    const int widx = blockIdx.x * 4 + wave;      // 0..5119
    const int rowblk = widx / 10, kt = widx - rowblk * 10;
    const int row = rowblk * 16 + frow;
    const float sc = 1.0f / fmaxf(sqrtf(rowssq[row]), 1e-12f);
    const float* zp = Z + (size_t)row * KP + kt * 32 + kg * 8;
    short8 hiv, lov;
    #pragma unroll
    for (int e = 0; e < 8; ++e) {
        unsigned short h_, l_;
        split_store(zp[e] * sc, &h_, &l_);
        hiv[e] = (short)h_; lov[e] = (short)l_;
    }
    size_t o = (size_t)widx * 512 + lane * 8;
    *(short8*)(Fhi + o) = hiv;
    *(short8*)(Flo + o) = lov;
}

// ---------------------------------------------------------------------------
// gemm_exp256: S0 = exp((f0 f1^T)/T)+eps, 256x256 tile, 8 waves (2x4).
// 2-D patch swizzle for per-XCD L2 residency.  (frozen from R10)
// ---------------------------------------------------------------------------
__global__ __launch_bounds__(512, 2) void gemm_exp256_kernel(
    const unsigned short* __restrict__ Fhi, const unsigned short* __restrict__ Flo,
    unsigned short* __restrict__ Sb, float* __restrict__ tpart)
{
    __shared__ unsigned short tile[128 * 256];
    __shared__ float colsum[256];

    const int p   = blockIdx.x & 7;
    const int idx = blockIdx.x >> 3;
    const int by  = (p >> 2) * 8 + (idx >> 2);
    const int bx  = (p & 3) * 4 + (idx & 3);
    const int brow = by * 256, bcol = bx * 256;

    const int tid  = threadIdx.x;
    const int wave = tid >> 6;
    const int lane = tid & 63;
    const int wm   = wave >> 2;
    const int wn   = wave & 3;
    const int frow = lane & 15;
    const int kgrp = lane >> 4;

    f32x4 acc[8][4];
    #pragma unroll
    for (int m = 0; m < 8; ++m)
        #pragma unroll
        for (int n = 0; n < 4; ++n) acc[m][n] = (f32x4)0.f;

    const int arb = by * 16 + wm * 8;
    const int brb = 256 + bx * 16 + wn * 4;
    const size_t lo8 = (size_t)lane * 8;

    for (int kt = 0; kt < NKT; ++kt) {
        short8 bhi[4], blo[4];
        #pragma unroll
        for (int n = 0; n < 4; ++n) {
            size_t b = (size_t)((brb + n) * NKT + kt) * 512 + lo8;
            bhi[n] = *(const short8*)(Fhi + b);
            blo[n] = *(const short8*)(Flo + b);
        }
        short8 ahi[8], alo[8];
        #pragma unroll
        for (int m = 0; m < 8; ++m) {
            size_t b = (size_t)((arb + m) * NKT + kt) * 512 + lo8;
            ahi[m] = *(const short8*)(Fhi + b);
            alo[m] = *(const short8*)(Flo + b);
        }
        #pragma unroll
        for (int m = 0; m < 8; ++m)
            #pragma unroll
            for (int n = 0; n < 4; ++n) {
                acc[m][n] = __builtin_amdgcn_mfma_f32_16x16x32_bf16(ahi[m], bhi[n], acc[m][n], 0, 0, 0);
                acc[m][n] = __builtin_amdgcn_mfma_f32_16x16x32_bf16(ahi[m], blo[n], acc[m][n], 0, 0, 0);
                acc[m][n] = __builtin_amdgcn_mfma_f32_16x16x32_bf16(alo[m], bhi[n], acc[m][n], 0, 0, 0);
            }
    }

    const float SCALE = 36.067376022224085f;
    if (tid < 256) colsum[tid] = 0.f;
    __syncthreads();

    for (int pass = 0; pass < 2; ++pass) {
        if (wm == pass) {
            #pragma unroll
            for (int n = 0; n < 4; ++n) {
                const int cl = wn * 64 + n * 16 + frow;
                float cp = 0.f;
                #pragma unroll
                for (int m = 0; m < 8; ++m) {
                    const int rl = m * 16 + kgrp * 4;
                    f32x4 a = acc[m][n];
                    #pragma unroll
                    for (int q = 0; q < 4; ++q) {
                        float sv = exp2f(a[q] * SCALE) + 1e-10f;
                        cp += sv;
                        tile[(rl + q) * 256 + cl] = f2bfu(sv);
                    }
                }
                atomicAdd(&colsum[cl], cp);
            }
        }
        __syncthreads();
        const int rbase = brow + pass * 128;
        for (int i = tid; i < 128 * 256 / 8; i += 512) {
            int row = i >> 5, ch = i & 31;
            *(short8*)(Sb + (size_t)(rbase + row) * NN + bcol + ch * 8) =
                *(const short8*)(tile + row * 256 + ch * 8);
        }
        __syncthreads();
    }
    if (tid < 256) tpart[(size_t)by * NN + bcol + tid] = colsum[tid];
}

// ---------------------------------------------------------------------------
// fallback gemm_exp (fp32 S, atomic colsums) for small-ws path
// ---------------------------------------------------------------------------
__global__ __launch_bounds__(256) void gemm_exp_kernel(
    const unsigned short* __restrict__ Ahi, const unsigned short* __restrict__ Alo,
    const unsigned short* __restrict__ Bhi, const unsigned short* __restrict__ Blo,
    float* __restrict__ S, float* __restrict__ tcol)
{
    __shared__ float colsum[BN];
    const int bx = blockIdx.x & 31;
    const int by = blockIdx.x >> 5;
    const int brow = by * BM, bcol = bx * BN;
    GEMM_FRAG_CORE(Ahi, Alo, Bhi, Blo, by * 8, 256 + bx * 8)

    const float SCALE = 36.067376022224085f;
    if (tid < BN) colsum[tid] = 0.f;
    __syncthreads();
    #pragma unroll
    for (int n = 0; n < 4; ++n) {
        const int col = bcol + wn * 64 + n * 16 + frow;
        float cp = 0.f;
        #pragma unroll
        for (int m = 0; m < 4; ++m) {
            const int rbase = brow + wm * 64 + m * 16 + kgrp * 4;
            f32x4 a = acc[m][n];
            #pragma unroll
            for (int q = 0; q < 4; ++q) {
                float sv = exp2f(a[q] * SCALE) + 1e-10f;
                S[(size_t)(rbase + q) * NN + col] = sv;
                cp += sv;
            }
        }
        atomicAdd(&colsum[wn * 64 + n * 16 + frow], cp);
    }
    __syncthreads();
    if (tid < BN) atomicAdd(&tcol[bcol + tid], colsum[tid]);
}

// ---------------------------------------------------------------------------
// reduce_part: dst[col] = sum_{k<np} part[k*NN + col]   (grid 16 x 256)
// ---------------------------------------------------------------------------
__global__ __launch_bounds__(256) void reduce_part_kernel(
    const float* __restrict__ part, float* __restrict__ dst, int np)
{
    const int col = blockIdx.x * 256 + threadIdx.x;
    float a0 = 0.f, a1 = 0.f, a2 = 0.f, a3 = 0.f;
    int k = 0;
    for (; k + 3 < np; k += 4) {
        a0 += part[(size_t)k * NN + col];
        a1 += part[(size_t)(k + 1) * NN + col];
        a2 += part[(size_t)(k + 2) * NN + col];
        a3 += part[(size_t)(k + 3) * NN + col];
    }
    for (; k < np; ++k) a0 += part[(size_t)k * NN + col];
    dst[col] = (a0 + a1) + (a2 + a3);
}

// reduce 256-deep partials: 64 blocks x 256 thr
__global__ __launch_bounds__(256) void reduce256_kernel(
    const float* __restrict__ part, float* __restrict__ dst)
{
    __shared__ float red[4][64];
    const int tid = threadIdx.x;
    const int col = blockIdx.x * 64 + (tid & 63);
    const int grp = tid >> 6;
    float s = 0.f;
    #pragma unroll 4
    for (int k = grp * 64; k < grp * 64 + 64; ++k)
        s += part[(size_t)k * NN + col];
    red[grp][tid & 63] = s;
    __syncthreads();
    if (tid < 64)
        dst[col] = (red[0][tid] + red[1][tid]) + (red[2][tid] + red[3][tid]);
}

// ---------------------------------------------------------------------------
// fused_pass: one Sinkhorn (row,col) pair, stripe held in REGISTERS.
// 256 blocks x 512 threads; block owns 16 rows; thread holds 16 uint4.
// ---------------------------------------------------------------------------
__global__ __launch_bounds__(512, 2) void fused_pass_b16(
    const unsigned short* __restrict__ Sb, const float* __restrict__ t,
    float* __restrict__ part)
{
    __shared__ float vs[NN];
    __shared__ float red[16][8];
    __shared__ float us[16];
    const int tid = threadIdx.x;
    const int wave = tid >> 6, lane = tid & 63;
    for (int i = tid; i < NN / 4; i += 512) {
        float4 tv = ((const float4*)t)[i];
        float4 vv;
        vv.x = 1.0f / tv.x; vv.y = 1.0f / tv.y;
        vv.z = 1.0f / tv.z; vv.w = 1.0f / tv.w;
        ((float4*)vs)[i] = vv;
    }
    __syncthreads();
    const float4* vs4 = (const float4*)vs;
    const float4 va = vs4[tid * 2], vb = vs4[tid * 2 + 1];
    const int row0 = blockIdx.x * 16;

    uint4 rv[16];
    #pragma unroll
    for (int r = 0; r < 16; ++r) {
        rv[r] = *(const uint4*)(Sb + (size_t)(row0 + r) * NN + tid * 8);
        float p = 0.f;
        p = fmaf(bflo(rv[r].x), va.x, p);
        p = fmaf(bfhi(rv[r].x), va.y, p);
        p = fmaf(bflo(rv[r].y), va.z, p);
        p = fmaf(bfhi(rv[r].y), va.w, p);
        p = fmaf(bflo(rv[r].z), vb.x, p);
        p = fmaf(bfhi(rv[r].z), vb.y, p);
        p = fmaf(bflo(rv[r].w), vb.z, p);
        p = fmaf(bfhi(rv[r].w), vb.w, p);
        #pragma unroll
        for (int off = 32; off >= 1; off >>= 1) p += __shfl_down(p, off, 64);
        if (lane == 0) red[r][wave] = p;
    }
    __syncthreads();
    if (tid < 16) {
        float s = 0.f;
        #pragma unroll
        for (int w = 0; w < 8; ++w) s += red[tid][w];
        us[tid] = 1.0f / s;
    }
    __syncthreads();

    float a[8];
    #pragma unroll
    for (int e = 0; e < 8; ++e) a[e] = 0.f;
    #pragma unroll
    for (int r = 0; r < 16; ++r) {
        const float ur = us[r];
        a[0] = fmaf(bflo(rv[r].x), ur, a[0]);
        a[1] = fmaf(bfhi(rv[r].x), ur, a[1]);
        a[2] = fmaf(bflo(rv[r].y), ur, a[2]);
        a[3] = fmaf(bfhi(rv[r].y), ur, a[3]);
        a[4] = fmaf(bflo(rv[r].z), ur, a[4]);
        a[5] = fmaf(bfhi(rv[r].z), ur, a[5]);
        a[6] = fmaf(bflo(rv[r].w), ur, a[6]);
        a[7] = fmaf(bfhi(rv[r].w), ur, a[7]);
    }
    float* pp = part + (size_t)blockIdx.x * NN + tid * 8;
    *(float4*)(pp)     = make_float4(a[0], a[1], a[2], a[3]);
    *(float4*)(pp + 4) = make_float4(a[4], a[5], a[6], a[7]);
}

// ---------------------------------------------------------------------------
// final512: u_i = 1/(Sb_i . v); Out = u_i * Sb_ij * v_j.
// ---------------------------------------------------------------------------
__global__ __launch_bounds__(512, 2) void final512_kernel(
    const unsigned short* __restrict__ Sb, const float* __restrict__ t,
    float* __restrict__ Out)
{
    __shared__ float vs[NN];
    __shared__ float red[16][8];
    __shared__ float us[16];
    const int tid = threadIdx.x;
    const int wave = tid >> 6, lane = tid & 63;
    for (int i = tid; i < NN / 4; i += 512) {
        float4 tv = ((const float4*)t)[i];
        float4 vv;
        vv.x = 1.0f / tv.x; vv.y = 1.0f / tv.y;
        vv.z = 1.0f / tv.z; vv.w = 1.0f / tv.w;
        ((float4*)vs)[i] = vv;
    }
    __syncthreads();
    const float4* vs4 = (const float4*)vs;
    const float4 va = vs4[tid * 2], vb = vs4[tid * 2 + 1];
    const int row0 = blockIdx.x * 16;

    uint4 rv[16];
    #pragma unroll
    for (int r = 0; r < 16; ++r) {
        rv[r] = *(const uint4*)(Sb + (size_t)(row0 + r) * NN + tid * 8);
        float p = 0.f;
        p = fmaf(bflo(rv[r].x), va.x, p);
        p = fmaf(bfhi(rv[r].x), va.y, p);
        p = fmaf(bflo(rv[r].y), va.z, p);
        p = fmaf(bfhi(rv[r].y), va.w, p);
        p = fmaf(bflo(rv[r].z), vb.x, p);
        p = fmaf(bfhi(rv[r].z), vb.y, p);
        p = fmaf(bflo(rv[r].w), vb.z, p);
        p = fmaf(bfhi(rv[r].w), vb.w, p);
        #pragma unroll
        for (int off = 32; off >= 1; off >>= 1) p += __shfl_down(p, off, 64);
        if (lane == 0) red[r][wave] = p;
    }
    __syncthreads();
    if (tid < 16) {
        float s = 0.f;
        #pragma unroll
        for (int w = 0; w < 8; ++w) s += red[tid][w];
        us[tid] = 1.0f / s;
    }
    __syncthreads();

    #pragma unroll
    for (int r = 0; r < 16; ++r) {
        const float ui = us[r];
        float* outp = Out + (size_t)(row0 + r) * NN + tid * 8;
        float4 o0, o1;
        o0.x = bflo(rv[r].x) * ui * va.x;
        o0.y = bfhi(rv[r].x) * ui * va.y;
        o0.z = bflo(rv[r].y) * ui * va.z;
        o0.w = bfhi(rv[r].y) * ui * va.w;
        o1.x = bflo(rv[r].z) * ui * vb.x;
        o1.y = bfhi(rv[r].z) * ui * vb.y;
        o1.z = bflo(rv[r].w) * ui * vb.z;
        o1.w = bfhi(rv[r].w) * ui * vb.w;
        *(float4*)(outp)     = o0;
        *(float4*)(outp + 4) = o1;
    }
}

// ---------------- fp32 fallback Sinkhorn (small-ws path) -------------------
#define RROWS 8
__global__ __launch_bounds__(256) void row_pass_f32(
    const float* __restrict__ S, const float* __restrict__ t, float* __restrict__ u)
{
    __shared__ float vs[NN];
    __shared__ float red[RROWS][4];
    const int tid = threadIdx.x;
    const int wave = tid >> 6, lane = tid & 63;
    for (int i = tid; i < NN; i += 256) vs[i] = 1.0f / t[i];
    __syncthreads();
    const int row0 = blockIdx.x * RROWS;
    for (int rr = 0; rr < RROWS; ++rr) {
        const float4* rowp = (const float4*)(S + (size_t)(row0 + rr) * NN);
        float part = 0.f;
        #pragma unroll 4
        for (int c4 = tid; c4 < NN / 4; c4 += 256) {
            float4 sv = rowp[c4];
            float4 vv = ((const float4*)vs)[c4];
            part += sv.x * vv.x + sv.y * vv.y + sv.z * vv.z + sv.w * vv.w;
        }
        #pragma unroll
        for (int off = 32; off >= 1; off >>= 1) part += __shfl_down(part, off, 64);
        if (lane == 0) red[rr][wave] = part;
    }
    __syncthreads();
    if (tid < RROWS) {
        float rs = red[tid][0] + red[tid][1] + red[tid][2] + red[tid][3];
        u[row0 + tid] = 1.0f / rs;
    }
}

__global__ __launch_bounds__(256) void col_pass_f32(
    const float* __restrict__ S, const float* __restrict__ u, float* __restrict__ t)
{
    __shared__ float us[32];
    const int tid = threadIdx.x;
    const int cb = blockIdx.x & 3;
    const int rbk = blockIdx.x >> 2;
    const int col0 = cb * 1024 + tid * 4;
    const int row0 = rbk * 32;
    if (tid < 32) us[tid] = u[row0 + tid];
    __syncthreads();
    float a0 = 0, a1 = 0, a2 = 0, a3 = 0;
    #pragma unroll 8
    for (int r = 0; r < 32; ++r) {
        float4 sv = *(const float4*)(S + (size_t)(row0 + r) * NN + col0);
        float ur = us[r];
        a0 = fmaf(sv.x, ur, a0);
        a1 = fmaf(sv.y, ur, a1);
        a2 = fmaf(sv.z, ur, a2);
        a3 = fmaf(sv.w, ur, a3);
    }
    atomicAdd(&t[col0 + 0], a0);
    atomicAdd(&t[col0 + 1], a1);
    atomicAdd(&t[col0 + 2], a2);
    atomicAdd(&t[col0 + 3], a3);
}

__global__ __launch_bounds__(256) void final_f32_kernel(
    float* __restrict__ S, const float* __restrict__ t)
{
    __shared__ float vs[NN];
    const int tid = threadIdx.x;
    const int wave = tid >> 6, lane = tid & 63;
    for (int i = tid; i < NN; i += 256) vs[i] = 1.0f / t[i];
    __syncthreads();
    const int row0 = blockIdx.x * 8 + wave * 2;
    for (int rr = 0; rr < 2; ++rr) {
        float4* rowp = (float4*)(S + (size_t)(row0 + rr) * NN);
        float4 rv[16];
        #pragma unroll
        for (int ii = 0; ii < 16; ++ii) rv[ii] = rowp[lane + 64 * ii];
        float part = 0.f;
        #pragma unroll
        for (int ii = 0; ii < 16; ++ii) {
            float4 vv = ((const float4*)vs)[lane + 64 * ii];
            part += rv[ii].x * vv.x + rv[ii].y * vv.y + rv[ii].z * vv.z + rv[ii].w * vv.w;
        }
        #pragma unroll
        for (int off = 32; off >= 1; off >>= 1) part += __shfl_down(part, off, 64);
        part = __shfl(part, 0, 64);
        const float ui = 1.0f / part;
        #pragma unroll
        for (int ii = 0; ii < 16; ++ii) {
            int c4 = lane + 64 * ii;
            float4 vv = ((const float4*)vs)[c4];
            float4 o = rv[ii];
            o.x *= ui * vv.x;
            o.y *= ui * vv.y;
            o.z *= ui * vv.z;
            o.w *= ui * vv.w;
            rowp[c4] = o;
        }
    }
}

// ---------------------------------------------------------------------------
extern "C" void kernel_launch(void* const* d_in, const int* in_sizes, int n_in,
                              void* d_out, int out_size, void* d_ws, size_t ws_size,
                              hipStream_t stream)
{
    (void)in_sizes; (void)n_in; (void)out_size;
    const float* h0 = (const float*)d_in[0];
    const float* h1 = (const float*)d_in[1];
    const float* W1 = (const float*)d_in[2];
    const float* b1 = (const float*)d_in[3];
    const float* W2 = (const float*)d_in[4];
    const float* b2 = (const float*)d_in[5];
    float* S = (float*)d_out;

    // ---- workspace: Fhi/Flo (frag-major), Sb, u, t[5] ----
    char* ws = (char*)d_ws;
    const size_t FROW = (size_t)2 * NN * KP;          // 8192 x 320 elements
    const size_t FSZB = FROW * sizeof(unsigned short);
    unsigned short* Fhi = (unsigned short*)(ws);
    unsigned short* Flo = (unsigned short*)(ws + FSZB);
    const size_t SBSZ = (size_t)NN * NN * sizeof(unsigned short);
    const size_t TAILSZ = 6 * (size_t)NN * sizeof(float);
    const bool big = ws_size >= 2 * FSZB + SBSZ + TAILSZ;
    unsigned short* Sb = big ? (unsigned short*)(ws + 2 * FSZB) : nullptr;
    char* tail = ws + 2 * FSZB + (big ? SBSZ : 0);
    float* u = (float*)(tail);
    float* t = (float*)(tail + NN * sizeof(float));   // t[5] contiguous

    // ---- transient scratch inside d_out (dead until final writes S) ----
    unsigned short* usp = (unsigned short*)d_out;
    unsigned short* Hhi = usp;
    unsigned short* Hlo = usp + FROW;
    unsigned short* Yhi = usp + 2 * FROW;
    unsigned short* Ylo = usp + 3 * FROW;
    const size_t WSZ = (size_t)NPAD * KP;             // 384*320
    unsigned short* W1th = usp + 4 * FROW;
    unsigned short* W1tl = W1th + WSZ;
    unsigned short* W2th = W1tl + WSZ;
    unsigned short* W2tl = W2th + WSZ;
    char* zb = (char*)(W2tl + WSZ);
    float* Z      = (float*)zb;                       // 8192 x 320 fp32
    float* rowssq = (float*)(zb + FROW * sizeof(float));
    float* b1p    = rowssq + 2 * NN;
    float* b2p    = b1p + NPAD;
    float* tpart   = b2p + NPAD;                      // 16 x 4096 (gemm_exp256)
    float* colpart = tpart + 32 * NN;                 // 256 x 4096 (fused passes)

    prep_kernel<<<1433, 256, 0, stream>>>(h0, h1, W1, W2, b1, b2,
                                          Hhi, Hlo, W1th, W1tl, W2th, W2tl,
                                          b1p, b2p, rowssq);
    gemm_l1_kernel<<<192, 256, 0, stream>>>(Hhi, Hlo, W1th, W1tl, b1p, Yhi, Ylo);
    gemm_l2_kernel<<<192, 256, 0, stream>>>(Yhi, Ylo, W2th, W2tl, b2p, Z, rowssq);
    normalize_kernel<<<1280, 256, 0, stream>>>(Z, rowssq, Fhi, Flo);

    if (big) {
        gemm_exp256_kernel<<<256, 512, 0, stream>>>(Fhi, Flo, Sb, tpart);
        reduce_part_kernel<<<16, 256, 0, stream>>>(tpart, t, 16);       // t[0]
        for (int it = 0; it < 4; ++it) {                                // i = 1..8
            fused_pass_b16<<<256, 512, 0, stream>>>(Sb, t + it * NN, colpart);
            reduce256_kernel<<<64, 256, 0, stream>>>(colpart, t + (it + 1) * NN);
        }
        final512_kernel<<<256, 512, 0, stream>>>(Sb, t + 4 * NN, S);    // i=9 + out
    } else {
        hipMemsetAsync(t, 0, 5 * NN * sizeof(float), stream);
        gemm_exp_kernel<<<1024, 256, 0, stream>>>(Fhi, Flo, Fhi, Flo, S, t);
        for (int it = 0; it < 4; ++it) {
            row_pass_f32<<<512, 256, 0, stream>>>(S, t + it * NN, u);
            col_pass_f32<<<512, 256, 0, stream>>>(S, u, t + (it + 1) * NN);
        }
        final_f32_kernel<<<512, 256, 0, stream>>>(S, t + 4 * NN);
    }
}

// Round 16
// 207.236 us; speedup vs baseline: 4.1358x; 1.0039x over previous
//
#include <hip/hip_runtime.h>
#include <hip/hip_bf16.h>
#include <stdint.h>

#define NN 4096
#define EMB 300
#define KP  320           // padded K for all GEMMs
#define NKT 10            // KP / 32
#define NPAD 384          // padded N for MLP weight tiles (3 x 128)

typedef __attribute__((ext_vector_type(8))) short short8;
typedef __attribute__((ext_vector_type(4))) float f32x4;

__device__ __forceinline__ float bf2f(unsigned short b) {
    return __uint_as_float(((unsigned int)b) << 16);
}
__device__ __forceinline__ float bflo(unsigned int u) {
    return __uint_as_float(u << 16);
}
__device__ __forceinline__ float bfhi(unsigned int u) {
    return __uint_as_float(u & 0xFFFF0000u);
}
__device__ __forceinline__ void split_store(float f, unsigned short* hi, unsigned short* lo) {
    __hip_bfloat16 hb = __float2bfloat16(f);
    float hf = __bfloat162float(hb);
    __hip_bfloat16 lb = __float2bfloat16(f - hf);
    *hi = *reinterpret_cast<unsigned short*>(&hb);
    *lo = *reinterpret_cast<unsigned short*>(&lb);
}
__device__ __forceinline__ unsigned short f2bfu(float f) {
    __hip_bfloat16 hb = __float2bfloat16(f);
    return *reinterpret_cast<unsigned short*>(&hb);
}

// Fragment-major layout for a [rows x 320] MFMA operand:
//   element (rowblk*16 + frow, kt*32 + kgrp*8 + e)  lives at
//   ((rowblk*NKT + kt)*64 + kgrp*16 + frow)*8 + e
__device__ __forceinline__ size_t fidx(int rowblk, int kt, int frow, int kgrp, int e) {
    return ((size_t)(rowblk * NKT + kt) * 64 + kgrp * 16 + frow) * 8 + e;
}

// ---------------------------------------------------------------------------
// prep_kernel: wave-per-tile (lane = kg*16+frow -> coalesced 1KB tile writes)
// ---------------------------------------------------------------------------
__global__ __launch_bounds__(256) void prep_kernel(
    const float* __restrict__ h0, const float* __restrict__ h1,
    const float* __restrict__ W1, const float* __restrict__ W2,
    const float* __restrict__ b1, const float* __restrict__ b2,
    unsigned short* __restrict__ Hhi, unsigned short* __restrict__ Hlo,
    unsigned short* __restrict__ W1th, unsigned short* __restrict__ W1tl,
    unsigned short* __restrict__ W2th, unsigned short* __restrict__ W2tl,
    float* __restrict__ b1p, float* __restrict__ b2p, float* __restrict__ rowssq)
{
    const int blk = blockIdx.x;
    const int tid = threadIdx.x;
    const int wave = tid >> 6, lane = tid & 63;
    const int kg = lane >> 4, frow = lane & 15;
    const int widx = blk * 4 + wave;

    if (widx < 5120) {                       // split_h: rowblk 0..511, kt 0..9
        const int rowblk = widx / 10, kt = widx - rowblk * 10;
        const int row = rowblk * 16 + frow;
        const float* hp = (row < NN) ? h0 + (size_t)row * EMB
                                     : h1 + (size_t)(row - NN) * EMB;
        const int c0 = kt * 32 + kg * 8;
        short8 hiv, lov;
        #pragma unroll
        for (int e = 0; e < 8; ++e) {
            float v = (c0 + e < EMB) ? hp[c0 + e] : 0.f;
            unsigned short h_, l_;
            split_store(v, &h_, &l_);
            hiv[e] = (short)h_; lov[e] = (short)l_;
        }
        size_t o = (size_t)widx * 512 + lane * 8;
        *(short8*)(Hhi + o) = hiv;
        *(short8*)(Hlo + o) = lov;
    } else if (widx < 5600) {                // W tiles: nblk 0..47, kt 0..9
        const int w2 = widx - 5120;
        const int nblk = w2 / 10, kt = w2 - nblk * 10;
        const int which = nblk >= 24;
        const int nb = nblk - which * 24;
        const int nl = nb * 16 + frow;
        const float* W = which ? W2 : W1;
        unsigned short* Wh = which ? W2th : W1th;
        unsigned short* Wl = which ? W2tl : W1tl;
        const int k0 = kt * 32 + kg * 8;
        short8 hiv, lov;
        #pragma unroll
        for (int e = 0; e < 8; ++e) {
            int k = k0 + e;
            float v = (nl < EMB && k < EMB) ? W[(size_t)k * EMB + nl] : 0.f;
            unsigned short h_, l_;
            split_store(v, &h_, &l_);
            hiv[e] = (short)h_; lov[e] = (short)l_;
        }
        size_t o = (size_t)(nb * NKT + kt) * 512 + lane * 8;
        *(short8*)(Wh + o) = hiv;
        *(short8*)(Wl + o) = lov;
    } else if (blk >= 1400 && blk < 1432) {
        int i = (blk - 1400) * 256 + tid;
        rowssq[i] = 0.f;
    } else if (blk == 1432) {
        for (int x = tid; x < NPAD; x += 256) {
            b1p[x] = (x < EMB) ? b1[x] : 0.f;
            b2p[x] = (x < EMB) ? b2[x] : 0.f;
        }
    }
}

// ---------------------------------------------------------------------------
// Barrier-free fragment GEMM core: 128x128 tile, 4 waves (2x2), split-bf16.
// ---------------------------------------------------------------------------
#define BM 128
#define BN 128

#define GEMM_FRAG_CORE(Ahi_, Alo_, Bhi_, Blo_, ARB0, BRB0)                     \
    const int tid  = threadIdx.x;                                              \
    const int wave = tid >> 6;                                                 \
    const int lane = tid & 63;                                                 \
    const int wm   = wave >> 1, wn = wave & 1;                                 \
    const int frow = lane & 15;                                                \
    const int kgrp = lane >> 4;                                                \
    (void)tid;                                                                 \
    f32x4 acc[4][4];                                                           \
    _Pragma("unroll")                                                          \
    for (int m = 0; m < 4; ++m)                                                \
        _Pragma("unroll")                                                      \
        for (int n = 0; n < 4; ++n) acc[m][n] = (f32x4)0.f;                    \
    const int arb = (ARB0) + wm * 4;                                           \
    const int brb = (BRB0) + wn * 4;                                           \
    const size_t lo8 = (size_t)lane * 8;                                       \
    _Pragma("unroll 2")                                                        \
    for (int kt = 0; kt < NKT; ++kt) {                                         \
        short8 ahi[4], alo[4], bhi[4], blo[4];                                 \
        _Pragma("unroll")                                                      \
        for (int m = 0; m < 4; ++m) {                                          \
            size_t b = (size_t)((arb + m) * NKT + kt) * 512 + lo8;             \
            ahi[m] = *(const short8*)(Ahi_ + b);                               \
            alo[m] = *(const short8*)(Alo_ + b);                               \
        }                                                                      \
        _Pragma("unroll")                                                      \
        for (int n = 0; n < 4; ++n) {                                          \
            size_t b = (size_t)((brb + n) * NKT + kt) * 512 + lo8;             \
            bhi[n] = *(const short8*)(Bhi_ + b);                               \
            blo[n] = *(const short8*)(Blo_ + b);                               \
        }                                                                      \
        _Pragma("unroll")                                                      \
        for (int m = 0; m < 4; ++m)                                            \
            _Pragma("unroll")                                                  \
            for (int n = 0; n < 4; ++n) {                                      \
                acc[m][n] = __builtin_amdgcn_mfma_f32_16x16x32_bf16(ahi[m], bhi[n], acc[m][n], 0, 0, 0); \
                acc[m][n] = __builtin_amdgcn_mfma_f32_16x16x32_bf16(ahi[m], blo[n], acc[m][n], 0, 0, 0); \
                acc[m][n] = __builtin_amdgcn_mfma_f32_16x16x32_bf16(alo[m], bhi[n], acc[m][n], 0, 0, 0); \
            }                                                                  \
    }

// ---------------------------------------------------------------------------
// gemm_l1: Y = split( relu( H @ W1 + b1 ) )  -> Y fragment-major (LDS stage)
// ---------------------------------------------------------------------------
#define LP 136
__global__ __launch_bounds__(256) void gemm_l1_kernel(
    const unsigned short* __restrict__ Ahi, const unsigned short* __restrict__ Alo,
    const unsigned short* __restrict__ Bhi, const unsigned short* __restrict__ Blo,
    const float* __restrict__ b1p,
    unsigned short* __restrict__ Yhi, unsigned short* __restrict__ Ylo)
{
    __shared__ unsigned short lYhi[128 * LP];
    __shared__ unsigned short lYlo[128 * LP];
    const int bx = blockIdx.x % 3;
    const int by = blockIdx.x / 3;
    const int brow = by * BM, bcol = bx * BN;
    (void)brow;
    GEMM_FRAG_CORE(Ahi, Alo, Bhi, Blo, by * 8, bx * 8)

    #pragma unroll
    for (int n = 0; n < 4; ++n) {
        const int cl = wn * 64 + n * 16 + frow;
        const float bb = b1p[bcol + cl];
        #pragma unroll
        for (int m = 0; m < 4; ++m) {
            const int rl = wm * 64 + m * 16 + kgrp * 4;
            f32x4 a = acc[m][n];
            #pragma unroll
            for (int q = 0; q < 4; ++q) {
                float y = fmaxf(a[q] + bb, 0.f);
                unsigned short h_, l_;
                split_store(y, &h_, &l_);
                lYhi[(rl + q) * LP + cl] = h_;
                lYlo[(rl + q) * LP + cl] = l_;
            }
        }
    }
    __syncthreads();

    const int rbB = by * 8;
    const int ktB = bx * 4;
    for (int i = tid; i < 32 * 64; i += 256) {
        const int t = i >> 6, l = i & 63;
        const int rb = t >> 2, ktc = t & 3;
        const int gkt = ktB + ktc;
        if (gkt >= NKT) continue;
        const int row_l = rb * 16 + (l & 15);
        const int col_l = ktc * 32 + (l >> 4) * 8;
        size_t o = (size_t)((rbB + rb) * NKT + gkt) * 512 + l * 8;
        *(short8*)(Yhi + o) = *(const short8*)(lYhi + row_l * LP + col_l);
        *(short8*)(Ylo + o) = *(const short8*)(lYlo + row_l * LP + col_l);
    }
}

// ---------------------------------------------------------------------------
// gemm_l2: Z = Y @ W2 + b2 (fp32 row-major), rowssq[row] += sum_j Z^2
// ---------------------------------------------------------------------------
__global__ __launch_bounds__(256) void gemm_l2_kernel(
    const unsigned short* __restrict__ Ahi, const unsigned short* __restrict__ Alo,
    const unsigned short* __restrict__ Bhi, const unsigned short* __restrict__ Blo,
    const float* __restrict__ b2p,
    float* __restrict__ Z, float* __restrict__ rowssq)
{
    const int bx = blockIdx.x % 3;
    const int by = blockIdx.x / 3;
    const int brow = by * BM, bcol = bx * BN;
    GEMM_FRAG_CORE(Ahi, Alo, Bhi, Blo, by * 8, bx * 8)

    float sq[4][4];
    #pragma unroll
    for (int m = 0; m < 4; ++m)
        #pragma unroll
        for (int q = 0; q < 4; ++q) sq[m][q] = 0.f;

    #pragma unroll
    for (int n = 0; n < 4; ++n) {
        const int col = bcol + wn * 64 + n * 16 + frow;
        const float bb = b2p[col];
        const bool ok = col < KP;
        #pragma unroll
        for (int m = 0; m < 4; ++m) {
            const int rbase = brow + wm * 64 + m * 16 + kgrp * 4;
            f32x4 a = acc[m][n];
            #pragma unroll
            for (int q = 0; q < 4; ++q) {
                float z = a[q] + bb;
                if (ok) Z[(size_t)(rbase + q) * KP + col] = z;
                else    z = 0.f;
                sq[m][q] = fmaf(z, z, sq[m][q]);
            }
        }
    }
    #pragma unroll
    for (int m = 0; m < 4; ++m)
        #pragma unroll
        for (int q = 0; q < 4; ++q) {
            float v2 = sq[m][q];
            #pragma unroll
            for (int off = 1; off <= 8; off <<= 1) v2 += __shfl_xor(v2, off, 64);
            if ((lane & 15) == 0)
                atomicAdd(&rowssq[brow + wm * 64 + m * 16 + kgrp * 4 + q], v2);
        }
}

// ---------------------------------------------------------------------------
// normalize: wave-per-tile, coalesced frag-major writes.
// ---------------------------------------------------------------------------
__global__ __launch_bounds__(256) void normalize_kernel(
    const float* __restrict__ Z, const float* __restrict__ rowssq,
    unsigned short* __restrict__ Fhi, unsigned short* __restrict__ Flo)
{
    const int tid = threadIdx.x;
    const int wave = tid >> 6, lane = tid & 63;
    const int kg = lane >> 4, frow = lane & 15;
    const int widx = blockIdx.x * 4 + wave;
    const int rowblk = widx / 10, kt = widx - rowblk * 10;
    const int row = rowblk * 16 + frow;
    const float sc = 1.0f / fmaxf(sqrtf(rowssq[row]), 1e-12f);
    const float* zp = Z + (size_t)row * KP + kt * 32 + kg * 8;
    short8 hiv, lov;
    #pragma unroll
    for (int e = 0; e < 8; ++e) {
        unsigned short h_, l_;
        split_store(zp[e] * sc, &h_, &l_);
        hiv[e] = (short)h_; lov[e] = (short)l_;
    }
    size_t o = (size_t)widx * 512 + lane * 8;
    *(short8*)(Fhi + o) = hiv;
    *(short8*)(Flo + o) = lov;
}

// ---------------------------------------------------------------------------
// gemm_exp256: 256x256 tile, 8 waves (2x4), LDS double-buffered staging via
// global_load_lds (frag-major tiles are 1KB-linear -> wave-uniform base +
// lane*16B maps exactly).  Buffer layout per kt: 64 slots x 512 ushorts:
//   [Ahi 0..15][Alo 16..31][Bhi 32..47][Blo 48..63].
// Staging kt+1 overlaps MFMA of kt; operand values bit-identical to R15.
// ---------------------------------------------------------------------------
__global__ __launch_bounds__(512, 2) void gemm_exp256_kernel(
    const unsigned short* __restrict__ Fhi, const unsigned short* __restrict__ Flo,
    unsigned short* __restrict__ Sb, float* __restrict__ tpart)
{
    __shared__ unsigned short smem[2 * 64 * 512];   // 128 KB
    __shared__ float colsum[256];

    const int p   = blockIdx.x & 7;
    const int idx = blockIdx.x >> 3;
    const int by  = (p >> 2) * 8 + (idx >> 2);
    const int bx  = (p & 3) * 4 + (idx & 3);
    const int brow = by * 256, bcol = bx * 256;

    const int tid  = threadIdx.x;
    const int wave = tid >> 6;
    const int lane = tid & 63;
    const int wm   = wave >> 2;
    const int wn   = wave & 3;
    const int frow = lane & 15;
    const int kgrp = lane >> 4;

    const int arbase = by * 16;          // A rowblks (f0)
    const int brbase = 256 + bx * 16;    // B rowblks (f1)

    f32x4 acc[8][4];
    #pragma unroll
    for (int m = 0; m < 8; ++m)
        #pragma unroll
        for (int n = 0; n < 4; ++n) acc[m][n] = (f32x4)0.f;

    // stage 8 tiles (slots wave*8..wave*8+7) of buffer `buf` for K-step `kt`
    #define STAGE(buf, kt)                                                     \
        {                                                                      \
            unsigned short* base_ = smem + (buf) * 32768;                      \
            _Pragma("unroll")                                                  \
            for (int i_ = 0; i_ < 8; ++i_) {                                   \
                const int s_ = wave * 8 + i_;                                  \
                int rb_; const unsigned short* src_;                           \
                if (s_ < 16)      { rb_ = arbase + s_;        src_ = Fhi; }    \
                else if (s_ < 32) { rb_ = arbase + (s_ - 16); src_ = Flo; }    \
                else if (s_ < 48) { rb_ = brbase + (s_ - 32); src_ = Fhi; }    \
                else              { rb_ = brbase + (s_ - 48); src_ = Flo; }    \
                const unsigned short* g_ =                                     \
                    src_ + (size_t)(rb_ * NKT + (kt)) * 512 + lane * 8;        \
                __builtin_amdgcn_global_load_lds(                              \
                    (const __attribute__((address_space(1))) void*)g_,         \
                    (__attribute__((address_space(3))) void*)(base_ + s_ * 512), \
                    16, 0, 0);                                                 \
            }                                                                  \
        }

    STAGE(0, 0)
    for (int kt = 0; kt < NKT; ++kt) {
        __syncthreads();                          // drains staging of buf kt&1
        if (kt + 1 < NKT) STAGE((kt + 1) & 1, kt + 1)
        const unsigned short* bb = smem + (kt & 1) * 32768;
        short8 ahi[8], alo[8], bhi[4], blo[4];
        #pragma unroll
        for (int n = 0; n < 4; ++n) {
            bhi[n] = *(const short8*)(bb + (32 + wn * 4 + n) * 512 + lane * 8);
            blo[n] = *(const short8*)(bb + (48 + wn * 4 + n) * 512 + lane * 8);
        }
        #pragma unroll
        for (int m = 0; m < 8; ++m) {
            ahi[m] = *(const short8*)(bb + (wm * 8 + m) * 512 + lane * 8);
            alo[m] = *(const short8*)(bb + (16 + wm * 8 + m) * 512 + lane * 8);
        }
        #pragma unroll
        for (int m = 0; m < 8; ++m)
            #pragma unroll
            for (int n = 0; n < 4; ++n) {
                acc[m][n] = __builtin_amdgcn_mfma_f32_16x16x32_bf16(ahi[m], bhi[n], acc[m][n], 0, 0, 0);
                acc[m][n] = __builtin_amdgcn_mfma_f32_16x16x32_bf16(ahi[m], blo[n], acc[m][n], 0, 0, 0);
                acc[m][n] = __builtin_amdgcn_mfma_f32_16x16x32_bf16(alo[m], bhi[n], acc[m][n], 0, 0, 0);
            }
    }
    #undef STAGE

    const float SCALE = 36.067376022224085f;
    unsigned short* tile = smem;                  // reuse first 64KB
    if (tid < 256) colsum[tid] = 0.f;
    __syncthreads();

    for (int pass = 0; pass < 2; ++pass) {
        if (wm == pass) {
            #pragma unroll
            for (int n = 0; n < 4; ++n) {
                const int cl = wn * 64 + n * 16 + frow;
                float cp = 0.f;
                #pragma unroll
                for (int m = 0; m < 8; ++m) {
                    const int rl = m * 16 + kgrp * 4;
                    f32x4 a = acc[m][n];
                    #pragma unroll
                    for (int q = 0; q < 4; ++q) {
                        float sv = exp2f(a[q] * SCALE) + 1e-10f;
                        cp += sv;
                        tile[(rl + q) * 256 + cl] = f2bfu(sv);
                    }
                }
                atomicAdd(&colsum[cl], cp);
            }
        }
        __syncthreads();
        const int rbase = brow + pass * 128;
        for (int i = tid; i < 128 * 256 / 8; i += 512) {
            int row = i >> 5, ch = i & 31;
            *(short8*)(Sb + (size_t)(rbase + row) * NN + bcol + ch * 8) =
                *(const short8*)(tile + row * 256 + ch * 8);
        }
        __syncthreads();
    }
    if (tid < 256) tpart[(size_t)by * NN + bcol + tid] = colsum[tid];
}

// ---------------------------------------------------------------------------
// fallback gemm_exp (fp32 S, atomic colsums) for small-ws path
// ---------------------------------------------------------------------------
__global__ __launch_bounds__(256) void gemm_exp_kernel(
    const unsigned short* __restrict__ Ahi, const unsigned short* __restrict__ Alo,
    const unsigned short* __restrict__ Bhi, const unsigned short* __restrict__ Blo,
    float* __restrict__ S, float* __restrict__ tcol)
{
    __shared__ float colsum[BN];
    const int bx = blockIdx.x & 31;
    const int by = blockIdx.x >> 5;
    const int brow = by * BM, bcol = bx * BN;
    GEMM_FRAG_CORE(Ahi, Alo, Bhi, Blo, by * 8, 256 + bx * 8)

    const float SCALE = 36.067376022224085f;
    if (tid < BN) colsum[tid] = 0.f;
    __syncthreads();
    #pragma unroll
    for (int n = 0; n < 4; ++n) {
        const int col = bcol + wn * 64 + n * 16 + frow;
        float cp = 0.f;
        #pragma unroll
        for (int m = 0; m < 4; ++m) {
            const int rbase = brow + wm * 64 + m * 16 + kgrp * 4;
            f32x4 a = acc[m][n];
            #pragma unroll
            for (int q = 0; q < 4; ++q) {
                float sv = exp2f(a[q] * SCALE) + 1e-10f;
                S[(size_t)(rbase + q) * NN + col] = sv;
                cp += sv;
            }
        }
        atomicAdd(&colsum[wn * 64 + n * 16 + frow], cp);
    }
    __syncthreads();
    if (tid < BN) atomicAdd(&tcol[bcol + tid], colsum[tid]);
}

// ---------------------------------------------------------------------------
// reduce_part: dst[col] = sum_{k<np} part[k*NN + col]   (grid 16 x 256)
// ---------------------------------------------------------------------------
__global__ __launch_bounds__(256) void reduce_part_kernel(
    const float* __restrict__ part, float* __restrict__ dst, int np)
{
    const int col = blockIdx.x * 256 + threadIdx.x;
    float a0 = 0.f, a1 = 0.f, a2 = 0.f, a3 = 0.f;
    int k = 0;
    for (; k + 3 < np; k += 4) {
        a0 += part[(size_t)k * NN + col];
        a1 += part[(size_t)(k + 1) * NN + col];
        a2 += part[(size_t)(k + 2) * NN + col];
        a3 += part[(size_t)(k + 3) * NN + col];
    }
    for (; k < np; ++k) a0 += part[(size_t)k * NN + col];
    dst[col] = (a0 + a1) + (a2 + a3);
}

// reduce 256-deep partials: 64 blocks x 256 thr
__global__ __launch_bounds__(256) void reduce256_kernel(
    const float* __restrict__ part, float* __restrict__ dst)
{
    __shared__ float red[4][64];
    const int tid = threadIdx.x;
    const int col = blockIdx.x * 64 + (tid & 63);
    const int grp = tid >> 6;
    float s = 0.f;
    #pragma unroll 4
    for (int k = grp * 64; k < grp * 64 + 64; ++k)
        s += part[(size_t)k * NN + col];
    red[grp][tid & 63] = s;
    __syncthreads();
    if (tid < 64)
        dst[col] = (red[0][tid] + red[1][tid]) + (red[2][tid] + red[3][tid]);
}

// ---------------------------------------------------------------------------
// fused_pass: one Sinkhorn (row,col) pair, stripe held in REGISTERS.
// ---------------------------------------------------------------------------
__global__ __launch_bounds__(512, 2) void fused_pass_b16(
    const unsigned short* __restrict__ Sb, const float* __restrict__ t,
    float* __restrict__ part)
{
    __shared__ float vs[NN];
    __shared__ float red[16][8];
    __shared__ float us[16];
    const int tid = threadIdx.x;
    const int wave = tid >> 6, lane = tid & 63;
    for (int i = tid; i < NN / 4; i += 512) {
        float4 tv = ((const float4*)t)[i];
        float4 vv;
        vv.x = 1.0f / tv.x; vv.y = 1.0f / tv.y;
        vv.z = 1.0f / tv.z; vv.w = 1.0f / tv.w;
        ((float4*)vs)[i] = vv;
    }
    __syncthreads();
    const float4* vs4 = (const float4*)vs;
    const float4 va = vs4[tid * 2], vb = vs4[tid * 2 + 1];
    const int row0 = blockIdx.x * 16;

    uint4 rv[16];
    #pragma unroll
    for (int r = 0; r < 16; ++r) {
        rv[r] = *(const uint4*)(Sb + (size_t)(row0 + r) * NN + tid * 8);
        float p = 0.f;
        p = fmaf(bflo(rv[r].x), va.x, p);
        p = fmaf(bfhi(rv[r].x), va.y, p);
        p = fmaf(bflo(rv[r].y), va.z, p);
        p = fmaf(bfhi(rv[r].y), va.w, p);
        p = fmaf(bflo(rv[r].z), vb.x, p);
        p = fmaf(bfhi(rv[r].z), vb.y, p);
        p = fmaf(bflo(rv[r].w), vb.z, p);
        p = fmaf(bfhi(rv[r].w), vb.w, p);
        #pragma unroll
        for (int off = 32; off >= 1; off >>= 1) p += __shfl_down(p, off, 64);
        if (lane == 0) red[r][wave] = p;
    }
    __syncthreads();
    if (tid < 16) {
        float s = 0.f;
        #pragma unroll
        for (int w = 0; w < 8; ++w) s += red[tid][w];
        us[tid] = 1.0f / s;
    }
    __syncthreads();

    float a[8];
    #pragma unroll
    for (int e = 0; e < 8; ++e) a[e] = 0.f;
    #pragma unroll
    for (int r = 0; r < 16; ++r) {
        const float ur = us[r];
        a[0] = fmaf(bflo(rv[r].x), ur, a[0]);
        a[1] = fmaf(bfhi(rv[r].x), ur, a[1]);
        a[2] = fmaf(bflo(rv[r].y), ur, a[2]);
        a[3] = fmaf(bfhi(rv[r].y), ur, a[3]);
        a[4] = fmaf(bflo(rv[r].z), ur, a[4]);
        a[5] = fmaf(bfhi(rv[r].z), ur, a[5]);
        a[6] = fmaf(bflo(rv[r].w), ur, a[6]);
        a[7] = fmaf(bfhi(rv[r].w), ur, a[7]);
    }
    float* pp = part + (size_t)blockIdx.x * NN + tid * 8;
    *(float4*)(pp)     = make_float4(a[0], a[1], a[2], a[3]);
    *(float4*)(pp + 4) = make_float4(a[4], a[5], a[6], a[7]);
}

// ---------------------------------------------------------------------------
// final512: u_i = 1/(Sb_i . v); Out = u_i * Sb_ij * v_j.
// ---------------------------------------------------------------------------
__global__ __launch_bounds__(512, 2) void final512_kernel(
    const unsigned short* __restrict__ Sb, const float* __restrict__ t,
    float* __restrict__ Out)
{
    __shared__ float vs[NN];
    __shared__ float red[16][8];
    __shared__ float us[16];
    const int tid = threadIdx.x;
    const int wave = tid >> 6, lane = tid & 63;
    for (int i = tid; i < NN / 4; i += 512) {
        float4 tv = ((const float4*)t)[i];
        float4 vv;
        vv.x = 1.0f / tv.x; vv.y = 1.0f / tv.y;
        vv.z = 1.0f / tv.z; vv.w = 1.0f / tv.w;
        ((float4*)vs)[i] = vv;
    }
    __syncthreads();
    const float4* vs4 = (const float4*)vs;
    const float4 va = vs4[tid * 2], vb = vs4[tid * 2 + 1];
    const int row0 = blockIdx.x * 16;

    uint4 rv[16];
    #pragma unroll
    for (int r = 0; r < 16; ++r) {
        rv[r] = *(const uint4*)(Sb + (size_t)(row0 + r) * NN + tid * 8);
        float p = 0.f;
        p = fmaf(bflo(rv[r].x), va.x, p);
        p = fmaf(bfhi(rv[r].x), va.y, p);
        p = fmaf(bflo(rv[r].y), va.z, p);
        p = fmaf(bfhi(rv[r].y), va.w, p);
        p = fmaf(bflo(rv[r].z), vb.x, p);
        p = fmaf(bfhi(rv[r].z), vb.y, p);
        p = fmaf(bflo(rv[r].w), vb.z, p);
        p = fmaf(bfhi(rv[r].w), vb.w, p);
        #pragma unroll
        for (int off = 32; off >= 1; off >>= 1) p += __shfl_down(p, off, 64);
        if (lane == 0) red[r][wave] = p;
    }
    __syncthreads();
    if (tid < 16) {
        float s = 0.f;
        #pragma unroll
        for (int w = 0; w < 8; ++w) s += red[tid][w];
        us[tid] = 1.0f / s;
    }
    __syncthreads();

    #pragma unroll
    for (int r = 0; r < 16; ++r) {
        const float ui = us[r];
        float* outp = Out + (size_t)(row0 + r) * NN + tid * 8;
        float4 o0, o1;
        o0.x = bflo(rv[r].x) * ui * va.x;
        o0.y = bfhi(rv[r].x) * ui * va.y;
        o0.z = bflo(rv[r].y) * ui * va.z;
        o0.w = bfhi(rv[r].y) * ui * va.w;
        o1.x = bflo(rv[r].z) * ui * vb.x;
        o1.y = bfhi(rv[r].z) * ui * vb.y;
        o1.z = bflo(rv[r].w) * ui * vb.z;
        o1.w = bfhi(rv[r].w) * ui * vb.w;
        *(float4*)(outp)     = o0;
        *(float4*)(outp + 4) = o1;
    }
}

// ---------------- fp32 fallback Sinkhorn (small-ws path) -------------------
#define RROWS 8
__global__ __launch_bounds__(256) void row_pass_f32(
    const float* __restrict__ S, const float* __restrict__ t, float* __restrict__ u)
{
    __shared__ float vs[NN];
    __shared__ float red[RROWS][4];
    const int tid = threadIdx.x;
    const int wave = tid >> 6, lane = tid & 63;
    for (int i = tid; i < NN; i += 256) vs[i] = 1.0f / t[i];
    __syncthreads();
    const int row0 = blockIdx.x * RROWS;
    for (int rr = 0; rr < RROWS; ++rr) {
        const float4* rowp = (const float4*)(S + (size_t)(row0 + rr) * NN);
        float part = 0.f;
        #pragma unroll 4
        for (int c4 = tid; c4 < NN / 4; c4 += 256) {
            float4 sv = rowp[c4];
            float4 vv = ((const float4*)vs)[c4];
            part += sv.x * vv.x + sv.y * vv.y + sv.z * vv.z + sv.w * vv.w;
        }
        #pragma unroll
        for (int off = 32; off >= 1; off >>= 1) part += __shfl_down(part, off, 64);
        if (lane == 0) red[rr][wave] = part;
    }
    __syncthreads();
    if (tid < RROWS) {
        float rs = red[tid][0] + red[tid][1] + red[tid][2] + red[tid][3];
        u[row0 + tid] = 1.0f / rs;
    }
}

__global__ __launch_bounds__(256) void col_pass_f32(
    const float* __restrict__ S, const float* __restrict__ u, float* __restrict__ t)
{
    __shared__ float us[32];
    const int tid = threadIdx.x;
    const int cb = blockIdx.x & 3;
    const int rbk = blockIdx.x >> 2;
    const int col0 = cb * 1024 + tid * 4;
    const int row0 = rbk * 32;
    if (tid < 32) us[tid] = u[row0 + tid];
    __syncthreads();
    float a0 = 0, a1 = 0, a2 = 0, a3 = 0;
    #pragma unroll 8
    for (int r = 0; r < 32; ++r) {
        float4 sv = *(const float4*)(S + (size_t)(row0 + r) * NN + col0);
        float ur = us[r];
        a0 = fmaf(sv.x, ur, a0);
        a1 = fmaf(sv.y, ur, a1);
        a2 = fmaf(sv.z, ur, a2);
        a3 = fmaf(sv.w, ur, a3);
    }
    atomicAdd(&t[col0 + 0], a0);
    atomicAdd(&t[col0 + 1], a1);
    atomicAdd(&t[col0 + 2], a2);
    atomicAdd(&t[col0 + 3], a3);
}

__global__ __launch_bounds__(256) void final_f32_kernel(
    float* __restrict__ S, const float* __restrict__ t)
{
    __shared__ float vs[NN];
    const int tid = threadIdx.x;
    const int wave = tid >> 6, lane = tid & 63;
    for (int i = tid; i < NN; i += 256) vs[i] = 1.0f / t[i];
    __syncthreads();
    const int row0 = blockIdx.x * 8 + wave * 2;
    for (int rr = 0; rr < 2; ++rr) {
        float4* rowp = (float4*)(S + (size_t)(row0 + rr) * NN);
        float4 rv[16];
        #pragma unroll
        for (int ii = 0; ii < 16; ++ii) rv[ii] = rowp[lane + 64 * ii];
        float part = 0.f;
        #pragma unroll
        for (int ii = 0; ii < 16; ++ii) {
            float4 vv = ((const float4*)vs)[lane + 64 * ii];
            part += rv[ii].x * vv.x + rv[ii].y * vv.y + rv[ii].z * vv.z + rv[ii].w * vv.w;
        }
        #pragma unroll
        for (int off = 32; off >= 1; off >>= 1) part += __shfl_down(part, off, 64);
        part = __shfl(part, 0, 64);
        const float ui = 1.0f / part;
        #pragma unroll
        for (int ii = 0; ii < 16; ++ii) {
            int c4 = lane + 64 * ii;
            float4 vv = ((const float4*)vs)[c4];
            float4 o = rv[ii];
            o.x *= ui * vv.x;
            o.y *= ui * vv.y;
            o.z *= ui * vv.z;
            o.w *= ui * vv.w;
            rowp[c4] = o;
        }
    }
}

// ---------------------------------------------------------------------------
extern "C" void kernel_launch(void* const* d_in, const int* in_sizes, int n_in,
                              void* d_out, int out_size, void* d_ws, size_t ws_size,
                              hipStream_t stream)
{
    (void)in_sizes; (void)n_in; (void)out_size;
    const float* h0 = (const float*)d_in[0];
    const float* h1 = (const float*)d_in[1];
    const float* W1 = (const float*)d_in[2];
    const float* b1 = (const float*)d_in[3];
    const float* W2 = (const float*)d_in[4];
    const float* b2 = (const float*)d_in[5];
    float* S = (float*)d_out;

    // ---- workspace: Fhi/Flo (frag-major), Sb, u, t[5] ----
    char* ws = (char*)d_ws;
    const size_t FROW = (size_t)2 * NN * KP;          // 8192 x 320 elements
    const size_t FSZB = FROW * sizeof(unsigned short);
    unsigned short* Fhi = (unsigned short*)(ws);
    unsigned short* Flo = (unsigned short*)(ws + FSZB);
    const size_t SBSZ = (size_t)NN * NN * sizeof(unsigned short);
    const size_t TAILSZ = 6 * (size_t)NN * sizeof(float);
    const bool big = ws_size >= 2 * FSZB + SBSZ + TAILSZ;
    unsigned short* Sb = big ? (unsigned short*)(ws + 2 * FSZB) : nullptr;
    char* tail = ws + 2 * FSZB + (big ? SBSZ : 0);
    float* u = (float*)(tail);
    float* t = (float*)(tail + NN * sizeof(float));   // t[5] contiguous

    // ---- transient scratch inside d_out (dead until final writes S) ----
    unsigned short* usp = (unsigned short*)d_out;
    unsigned short* Hhi = usp;
    unsigned short* Hlo = usp + FROW;
    unsigned short* Yhi = usp + 2 * FROW;
    unsigned short* Ylo = usp + 3 * FROW;
    const size_t WSZ = (size_t)NPAD * KP;             // 384*320
    unsigned short* W1th = usp + 4 * FROW;
    unsigned short* W1tl = W1th + WSZ;
    unsigned short* W2th = W1tl + WSZ;
    unsigned short* W2tl = W2th + WSZ;
    char* zb = (char*)(W2tl + WSZ);
    float* Z      = (float*)zb;                       // 8192 x 320 fp32
    float* rowssq = (float*)(zb + FROW * sizeof(float));
    float* b1p    = rowssq + 2 * NN;
    float* b2p    = b1p + NPAD;
    float* tpart   = b2p + NPAD;                      // 16 x 4096 (gemm_exp256)
    float* colpart = tpart + 32 * NN;                 // 256 x 4096 (fused passes)

    prep_kernel<<<1433, 256, 0, stream>>>(h0, h1, W1, W2, b1, b2,
                                          Hhi, Hlo, W1th, W1tl, W2th, W2tl,
                                          b1p, b2p, rowssq);
    gemm_l1_kernel<<<192, 256, 0, stream>>>(Hhi, Hlo, W1th, W1tl, b1p, Yhi, Ylo);
    gemm_l2_kernel<<<192, 256, 0, stream>>>(Yhi, Ylo, W2th, W2tl, b2p, Z, rowssq);
    normalize_kernel<<<1280, 256, 0, stream>>>(Z, rowssq, Fhi, Flo);

    if (big) {
        gemm_exp256_kernel<<<256, 512, 0, stream>>>(Fhi, Flo, Sb, tpart);
        reduce_part_kernel<<<16, 256, 0, stream>>>(tpart, t, 16);       // t[0]
        for (int it = 0; it < 4; ++it) {                                // i = 1..8
            fused_pass_b16<<<256, 512, 0, stream>>>(Sb, t + it * NN, colpart);
            reduce256_kernel<<<64, 256, 0, stream>>>(colpart, t + (it + 1) * NN);
        }
        final512_kernel<<<256, 512, 0, stream>>>(Sb, t + 4 * NN, S);    // i=9 + out
    } else {
        hipMemsetAsync(t, 0, 5 * NN * sizeof(float), stream);
        gemm_exp_kernel<<<1024, 256, 0, stream>>>(Fhi, Flo, Fhi, Flo, S, t);
        for (int it = 0; it < 4; ++it) {
            row_pass_f32<<<512, 256, 0, stream>>>(S, t + it * NN, u);
            col_pass_f32<<<512, 256, 0, stream>>>(S, u, t + (it + 1) * NN);
        }
        final_f32_kernel<<<512, 256, 0, stream>>>(S, t + 4 * NN);
    }
}